// Round 6
// baseline (756.574 us; speedup 1.0000x reference)
//
#include <hip/hip_runtime.h>

#define IN_F 256
#define OUT_F 64
#define LOGB 7            // 128 nodes per bucket
#define BNODES 128
#define MAXBUCK 1024      // supports N <= 131072

typedef __bf16 bf16x8 __attribute__((ext_vector_type(8)));
typedef float f32x4 __attribute__((ext_vector_type(4)));

// ---------------------------------------------------------------- W fragment prep
// Pack W [256][64] fp32 into bf16 MFMA B-fragments.
// grid 32 blocks (st = s*4+t), 64 threads (lane). B frag for k-step s, n-tile t:
// lane l holds W[32s + (l>>4)*8 + j][16t + (l&15)], j=0..7.
__global__ __launch_bounds__(64) void wfrag_kernel(const float* __restrict__ W,
                                                   __bf16* __restrict__ wfrag) {
    const int st = blockIdx.x;
    const int s = st >> 2, t = st & 3;
    const int l = threadIdx.x;
    const int n = t * 16 + (l & 15);
    const int k0 = s * 32 + (l >> 4) * 8;
    bf16x8 f;
#pragma unroll
    for (int j = 0; j < 8; ++j)
        f[j] = (__bf16)W[(k0 + j) * OUT_F + n];
    *(bf16x8*)(wfrag + (size_t)(st * 64 + l) * 8) = f;
}

// ---------------------------------------------------------------- MFMA GEMM h = feat @ W (bf16 out)
__global__ __launch_bounds__(256) void gemm_mfma_kernel(const float* __restrict__ feat,
                                                        const __bf16* __restrict__ wfrag,
                                                        __bf16* __restrict__ h, int N) {
    const int tid = threadIdx.x;
    const int wv = tid >> 6;
    const int l = tid & 63;
    const int m0 = blockIdx.x * 64 + wv * 16;
    const int q = l >> 4;
    const int row = min(m0 + (l & 15), N - 1);

    const float* __restrict__ arow = feat + (size_t)row * IN_F + q * 8;
    const bf16x8* __restrict__ wf = (const bf16x8*)wfrag; // [32 frags][64 lanes]

    f32x4 acc0 = {0.f, 0.f, 0.f, 0.f};
    f32x4 acc1 = {0.f, 0.f, 0.f, 0.f};
    f32x4 acc2 = {0.f, 0.f, 0.f, 0.f};
    f32x4 acc3 = {0.f, 0.f, 0.f, 0.f};

#pragma unroll
    for (int s = 0; s < 8; ++s) {
        float4 fa0 = *(const float4*)(arow + s * 32);
        float4 fa1 = *(const float4*)(arow + s * 32 + 4);
        bf16x8 a;
        a[0] = (__bf16)fa0.x; a[1] = (__bf16)fa0.y;
        a[2] = (__bf16)fa0.z; a[3] = (__bf16)fa0.w;
        a[4] = (__bf16)fa1.x; a[5] = (__bf16)fa1.y;
        a[6] = (__bf16)fa1.z; a[7] = (__bf16)fa1.w;
        bf16x8 b0 = wf[(s * 4 + 0) * 64 + l];
        bf16x8 b1 = wf[(s * 4 + 1) * 64 + l];
        bf16x8 b2 = wf[(s * 4 + 2) * 64 + l];
        bf16x8 b3 = wf[(s * 4 + 3) * 64 + l];
        acc0 = __builtin_amdgcn_mfma_f32_16x16x32_bf16(a, b0, acc0, 0, 0, 0);
        acc1 = __builtin_amdgcn_mfma_f32_16x16x32_bf16(a, b1, acc1, 0, 0, 0);
        acc2 = __builtin_amdgcn_mfma_f32_16x16x32_bf16(a, b2, acc2, 0, 0, 0);
        acc3 = __builtin_amdgcn_mfma_f32_16x16x32_bf16(a, b3, acc3, 0, 0, 0);
    }

    // D layout: col = lane&15, row = (lane>>4)*4 + reg
    const int colb = l & 15;
#pragma unroll
    for (int r = 0; r < 4; ++r) {
        int ro = m0 + q * 4 + r;
        if (ro < N) {
            __bf16* hp = h + (size_t)ro * OUT_F + colb;
            hp[0]  = (__bf16)acc0[r];
            hp[16] = (__bf16)acc1[r];
            hp[32] = (__bf16)acc2[r];
            hp[48] = (__bf16)acc3[r];
        }
    }
}

// ---------------------------------------------------------------- bucket histogram
// LDS-privatized histogram of dst>>LOGB; one global atomic per bucket per block.
__global__ __launch_bounds__(256) void bhist_kernel(const int* __restrict__ dst,
                                                    int* __restrict__ bcnt, int E, int nbuck) {
    __shared__ int hist[MAXBUCK];
    for (int i = threadIdx.x; i < nbuck; i += 256) hist[i] = 0;
    __syncthreads();
    const int stride = gridDim.x * 1024;
    for (int base = (blockIdx.x * 256 + threadIdx.x) * 4; base < E; base += stride) {
        if (base + 4 <= E) {
            int4 d4 = *(const int4*)(dst + base);
            atomicAdd(&hist[d4.x >> LOGB], 1);
            atomicAdd(&hist[d4.y >> LOGB], 1);
            atomicAdd(&hist[d4.z >> LOGB], 1);
            atomicAdd(&hist[d4.w >> LOGB], 1);
        } else {
            for (int e = base; e < E; ++e) atomicAdd(&hist[dst[e] >> LOGB], 1);
        }
    }
    __syncthreads();
    for (int i = threadIdx.x; i < nbuck; i += 256)
        if (hist[i]) atomicAdd(&bcnt[i], hist[i]);
}

// ---------------------------------------------------------------- bucket scan (1 block)
__global__ __launch_bounds__(1024) void bscan_kernel(const int* __restrict__ bcnt,
                                                     int* __restrict__ bbase,
                                                     int* __restrict__ bcursor, int nbuck) {
    __shared__ int s[1024];
    const int t = threadIdx.x;
    int v = (t < nbuck) ? bcnt[t] : 0;
    s[t] = v;
    __syncthreads();
    for (int o = 1; o < 1024; o <<= 1) {
        int x = (t >= o) ? s[t - o] : 0;
        __syncthreads();
        s[t] += x;
        __syncthreads();
    }
    if (t < nbuck) {
        int ex = s[t] - v;
        bbase[t] = ex;
        bcursor[t] = ex;
    }
    if (t == 0) bbase[nbuck] = s[1023]; // total = E
}

// ---------------------------------------------------------------- bucket scatter
// Block = 1024 threads x 4 edges. LDS count -> one reservation atomic per
// bucket per block -> append. Appends per bucket are contiguous (L2-local).
__global__ __launch_bounds__(1024) void bscatter_kernel(const int* __restrict__ src,
                                                        const int* __restrict__ dst,
                                                        const float* __restrict__ ew,
                                                        int* __restrict__ bcursor,
                                                        int2* __restrict__ payload,
                                                        int E, int nbuck) {
    __shared__ int cnt[MAXBUCK];
    __shared__ int basearr[MAXBUCK];
    const int t = threadIdx.x;
    for (int i = t; i < nbuck; i += 1024) cnt[i] = 0;
    __syncthreads();

    const int base = (blockIdx.x * 1024 + t) * 4;
    int dd[4] = {0, 0, 0, 0}, ss[4] = {0, 0, 0, 0};
    float ww[4] = {0.f, 0.f, 0.f, 0.f};
    int nv = 0;
    if (base + 4 <= E) {
        int4 d4 = *(const int4*)(dst + base);
        int4 s4 = *(const int4*)(src + base);
        float4 w4 = *(const float4*)(ew + base);
        dd[0] = d4.x; dd[1] = d4.y; dd[2] = d4.z; dd[3] = d4.w;
        ss[0] = s4.x; ss[1] = s4.y; ss[2] = s4.z; ss[3] = s4.w;
        ww[0] = w4.x; ww[1] = w4.y; ww[2] = w4.z; ww[3] = w4.w;
        nv = 4;
    } else if (base < E) {
        nv = E - base;
#pragma unroll 4
        for (int j = 0; j < 4; ++j)
            if (j < nv) { dd[j] = dst[base + j]; ss[j] = src[base + j]; ww[j] = ew[base + j]; }
    }

    int idx[4];
#pragma unroll 4
    for (int j = 0; j < 4; ++j)
        if (j < nv) idx[j] = atomicAdd(&cnt[dd[j] >> LOGB], 1);
    __syncthreads();

    for (int i = t; i < nbuck; i += 1024)
        if (cnt[i]) basearr[i] = atomicAdd(&bcursor[i], cnt[i]);
    __syncthreads();

#pragma unroll 4
    for (int j = 0; j < 4; ++j)
        if (j < nv) {
            int pos = basearr[dd[j] >> LOGB] + idx[j];
            payload[pos] = make_int2(ss[j] | ((dd[j] & (BNODES - 1)) << 25),
                                     __float_as_int(ww[j]));
        }
}

// ---------------------------------------------------------------- fused bucket gather + ReLU
// One block per bucket. LDS acc[128][64] f32; waves stream the bucket's edges
// with 4-deep MLP on the random h-row gathers; ds_add_f32 accumulate; then one
// contiguous float4 store of the bucket's 128 output rows.
__global__ __launch_bounds__(256) void bgather_kernel(const __bf16* __restrict__ h,
                                                      const int2* __restrict__ payload,
                                                      const int* __restrict__ bbase,
                                                      float* __restrict__ out, int N) {
    __shared__ float acc[BNODES * OUT_F]; // 32 KB
    const int t = threadIdx.x;
    const int wv = t >> 6, lane = t & 63;

    float4 z4 = {0.f, 0.f, 0.f, 0.f};
#pragma unroll
    for (int k = 0; k < 8; ++k)
        ((float4*)acc)[t * 8 + k] = z4;
    __syncthreads();

    const int b = bbase[blockIdx.x];
    const int e = bbase[blockIdx.x + 1];
    for (int i = b + wv * 4; i < e; i += 16) {
        const int n = min(4, e - i);
        int2 p[4];
        float hv[4];
#pragma unroll 4
        for (int j = 0; j < 4; ++j)
            if (j < n) p[j] = payload[i + j];
#pragma unroll 4
        for (int j = 0; j < 4; ++j)
            if (j < n) hv[j] = (float)h[(size_t)(p[j].x & 0x1FFFFFF) * OUT_F + lane];
#pragma unroll 4
        for (int j = 0; j < 4; ++j)
            if (j < n)
                atomicAdd(&acc[(((unsigned)p[j].x) >> 25) * OUT_F + lane],
                          hv[j] * __int_as_float(p[j].y));
    }
    __syncthreads();

    const int node0 = blockIdx.x << LOGB;
#pragma unroll
    for (int k = 0; k < 8; ++k) {
        int idx4 = t * 8 + k;          // 0..2047
        int row = idx4 >> 4;           // 0..127
        int g = node0 + row;
        if (g < N) {
            float4 v = ((float4*)acc)[idx4];
            v.x = fmaxf(v.x, 0.f);
            v.y = fmaxf(v.y, 0.f);
            v.z = fmaxf(v.z, 0.f);
            v.w = fmaxf(v.w, 0.f);
            ((float4*)out)[(size_t)g * (OUT_F / 4) + (idx4 & 15)] = v;
        }
    }
}

// ---------------------------------------------------------------- launch
extern "C" void kernel_launch(void* const* d_in, const int* in_sizes, int n_in,
                              void* d_out, int out_size, void* d_ws, size_t ws_size,
                              hipStream_t stream) {
    const float* feat = (const float*)d_in[0];
    const float* W    = (const float*)d_in[1];
    const float* ew   = (const float*)d_in[2];
    const int*   src  = (const int*)d_in[3];
    const int*   dst  = (const int*)d_in[4];
    float* out = (float*)d_out;

    const int N = in_sizes[0] / IN_F;
    const int E = in_sizes[2];
    const int nbuck = (N + BNODES - 1) >> LOGB;

    // workspace layout (payload first to keep int2 8B-aligned)
    char* ws = (char*)d_ws;
    int2*   payload = (int2*)ws;   ws += (size_t)E * 8;            // 12.8 MB
    __bf16* h       = (__bf16*)ws; ws += (size_t)N * OUT_F * 2;    // 12.8 MB
    __bf16* wfrag   = (__bf16*)ws; ws += 32 * 64 * 8 * 2;          // 32 KB
    int*    bcnt    = (int*)ws;    ws += (MAXBUCK + 1) * 4;
    int*    bbase   = (int*)ws;    ws += (MAXBUCK + 1) * 4;
    int*    bcursor = (int*)ws;                                    // MAXBUCK

    hipMemsetAsync(bcnt, 0, (size_t)nbuck * 4, stream);

    hipLaunchKernelGGL(wfrag_kernel, dim3(32), dim3(64), 0, stream, W, wfrag);
    hipLaunchKernelGGL(gemm_mfma_kernel, dim3((N + 63) / 64), dim3(256), 0, stream, feat, wfrag, h, N);
    hipLaunchKernelGGL(bhist_kernel, dim3(512), dim3(256), 0, stream, dst, bcnt, E, nbuck);
    hipLaunchKernelGGL(bscan_kernel, dim3(1), dim3(1024), 0, stream, bcnt, bbase, bcursor, nbuck);
    hipLaunchKernelGGL(bscatter_kernel, dim3((E + 4095) / 4096), dim3(1024), 0, stream,
                       src, dst, ew, bcursor, payload, E, nbuck);
    hipLaunchKernelGGL(bgather_kernel, dim3(nbuck), dim3(256), 0, stream, h, payload, bbase, out, N);
}

// Round 7
// 168.938 us; speedup vs baseline: 4.4784x; 4.4784x over previous
//
#include <hip/hip_runtime.h>

#define IN_F 256
#define OUT_F 64
#define LOGB 6            // 64 nodes per bucket
#define BNODES 64
#define MAXBUCK 2048      // supports N <= 131072
#define CAP 4096          // sorted edges per bucket (4x mean); tail handled correctly

typedef __bf16 bf16x8 __attribute__((ext_vector_type(8)));
typedef float f32x4 __attribute__((ext_vector_type(4)));

// ---------------------------------------------------------------- W fragment prep
__global__ __launch_bounds__(64) void wfrag_kernel(const float* __restrict__ W,
                                                   __bf16* __restrict__ wfrag) {
    const int st = blockIdx.x;
    const int s = st >> 2, t = st & 3;
    const int l = threadIdx.x;
    const int n = t * 16 + (l & 15);
    const int k0 = s * 32 + (l >> 4) * 8;
    bf16x8 f;
#pragma unroll
    for (int j = 0; j < 8; ++j)
        f[j] = (__bf16)W[(k0 + j) * OUT_F + n];
    *(bf16x8*)(wfrag + (size_t)(st * 64 + l) * 8) = f;
}

// ---------------------------------------------------------------- MFMA GEMM h = feat @ W (bf16 out)
__global__ __launch_bounds__(256) void gemm_mfma_kernel(const float* __restrict__ feat,
                                                        const __bf16* __restrict__ wfrag,
                                                        __bf16* __restrict__ h, int N) {
    const int tid = threadIdx.x;
    const int wv = tid >> 6;
    const int l = tid & 63;
    const int m0 = blockIdx.x * 64 + wv * 16;
    const int q = l >> 4;
    const int row = min(m0 + (l & 15), N - 1);

    const float* __restrict__ arow = feat + (size_t)row * IN_F + q * 8;
    const bf16x8* __restrict__ wf = (const bf16x8*)wfrag; // [32 frags][64 lanes]

    f32x4 acc0 = {0.f, 0.f, 0.f, 0.f};
    f32x4 acc1 = {0.f, 0.f, 0.f, 0.f};
    f32x4 acc2 = {0.f, 0.f, 0.f, 0.f};
    f32x4 acc3 = {0.f, 0.f, 0.f, 0.f};

#pragma unroll
    for (int s = 0; s < 8; ++s) {
        float4 fa0 = *(const float4*)(arow + s * 32);
        float4 fa1 = *(const float4*)(arow + s * 32 + 4);
        bf16x8 a;
        a[0] = (__bf16)fa0.x; a[1] = (__bf16)fa0.y;
        a[2] = (__bf16)fa0.z; a[3] = (__bf16)fa0.w;
        a[4] = (__bf16)fa1.x; a[5] = (__bf16)fa1.y;
        a[6] = (__bf16)fa1.z; a[7] = (__bf16)fa1.w;
        bf16x8 b0 = wf[(s * 4 + 0) * 64 + l];
        bf16x8 b1 = wf[(s * 4 + 1) * 64 + l];
        bf16x8 b2 = wf[(s * 4 + 2) * 64 + l];
        bf16x8 b3 = wf[(s * 4 + 3) * 64 + l];
        acc0 = __builtin_amdgcn_mfma_f32_16x16x32_bf16(a, b0, acc0, 0, 0, 0);
        acc1 = __builtin_amdgcn_mfma_f32_16x16x32_bf16(a, b1, acc1, 0, 0, 0);
        acc2 = __builtin_amdgcn_mfma_f32_16x16x32_bf16(a, b2, acc2, 0, 0, 0);
        acc3 = __builtin_amdgcn_mfma_f32_16x16x32_bf16(a, b3, acc3, 0, 0, 0);
    }

    const int colb = l & 15;
#pragma unroll
    for (int r = 0; r < 4; ++r) {
        int ro = m0 + q * 4 + r;
        if (ro < N) {
            __bf16* hp = h + (size_t)ro * OUT_F + colb;
            hp[0]  = (__bf16)acc0[r];
            hp[16] = (__bf16)acc1[r];
            hp[32] = (__bf16)acc2[r];
            hp[48] = (__bf16)acc3[r];
        }
    }
}

// ---------------------------------------------------------------- bucket histogram
__global__ __launch_bounds__(256) void bhist_kernel(const int* __restrict__ dst,
                                                    int* __restrict__ bcnt, int E, int nbuck) {
    __shared__ int hist[MAXBUCK];
    for (int i = threadIdx.x; i < nbuck; i += 256) hist[i] = 0;
    __syncthreads();
    const int stride = gridDim.x * 1024;
    for (int base = (blockIdx.x * 256 + threadIdx.x) * 4; base < E; base += stride) {
        if (base + 4 <= E) {
            int4 d4 = *(const int4*)(dst + base);
            atomicAdd(&hist[d4.x >> LOGB], 1);
            atomicAdd(&hist[d4.y >> LOGB], 1);
            atomicAdd(&hist[d4.z >> LOGB], 1);
            atomicAdd(&hist[d4.w >> LOGB], 1);
        } else {
            for (int e = base; e < E; ++e) atomicAdd(&hist[dst[e] >> LOGB], 1);
        }
    }
    __syncthreads();
    for (int i = threadIdx.x; i < nbuck; i += 256)
        if (hist[i]) atomicAdd(&bcnt[i], hist[i]);
}

// ---------------------------------------------------------------- bucket scan (1 block, nbuck <= 2048)
__global__ __launch_bounds__(1024) void bscan_kernel(const int* __restrict__ bcnt,
                                                     int* __restrict__ bbase,
                                                     int* __restrict__ bcursor, int nbuck) {
    __shared__ int s[1024];
    const int t = threadIdx.x;
    const int i0 = 2 * t, i1 = 2 * t + 1;
    int v0 = (i0 < nbuck) ? bcnt[i0] : 0;
    int v1 = (i1 < nbuck) ? bcnt[i1] : 0;
    s[t] = v0 + v1;
    __syncthreads();
    for (int o = 1; o < 1024; o <<= 1) {
        int x = (t >= o) ? s[t - o] : 0;
        __syncthreads();
        s[t] += x;
        __syncthreads();
    }
    int ex = s[t] - (v0 + v1);
    if (i0 < nbuck) { bbase[i0] = ex; bcursor[i0] = ex; }
    if (i1 < nbuck) { bbase[i1] = ex + v0; bcursor[i1] = ex + v0; }
    if (t == 0) bbase[nbuck] = s[1023];
}

// ---------------------------------------------------------------- bucket scatter
__global__ __launch_bounds__(1024) void bscatter_kernel(const int* __restrict__ src,
                                                        const int* __restrict__ dst,
                                                        const float* __restrict__ ew,
                                                        int* __restrict__ bcursor,
                                                        int2* __restrict__ payload,
                                                        int E, int nbuck) {
    __shared__ int cnt[MAXBUCK];
    __shared__ int basearr[MAXBUCK];
    const int t = threadIdx.x;
    for (int i = t; i < nbuck; i += 1024) cnt[i] = 0;
    __syncthreads();

    const int base = (blockIdx.x * 1024 + t) * 4;
    int dd[4] = {0, 0, 0, 0}, ss[4] = {0, 0, 0, 0};
    float ww[4] = {0.f, 0.f, 0.f, 0.f};
    int nv = 0;
    if (base + 4 <= E) {
        int4 d4 = *(const int4*)(dst + base);
        int4 s4 = *(const int4*)(src + base);
        float4 w4 = *(const float4*)(ew + base);
        dd[0] = d4.x; dd[1] = d4.y; dd[2] = d4.z; dd[3] = d4.w;
        ss[0] = s4.x; ss[1] = s4.y; ss[2] = s4.z; ss[3] = s4.w;
        ww[0] = w4.x; ww[1] = w4.y; ww[2] = w4.z; ww[3] = w4.w;
        nv = 4;
    } else if (base < E) {
        nv = E - base;
#pragma unroll 4
        for (int j = 0; j < 4; ++j)
            if (j < nv) { dd[j] = dst[base + j]; ss[j] = src[base + j]; ww[j] = ew[base + j]; }
    }

    int idx[4];
#pragma unroll 4
    for (int j = 0; j < 4; ++j)
        if (j < nv) idx[j] = atomicAdd(&cnt[dd[j] >> LOGB], 1);
    __syncthreads();

    for (int i = t; i < nbuck; i += 1024)
        if (cnt[i]) basearr[i] = atomicAdd(&bcursor[i], cnt[i]);
    __syncthreads();

#pragma unroll 4
    for (int j = 0; j < 4; ++j)
        if (j < nv) {
            int pos = basearr[dd[j] >> LOGB] + idx[j];
            payload[pos] = make_int2(ss[j] | ((dd[j] & (BNODES - 1)) << 25),
                                     __float_as_int(ww[j]));
        }
}

// ---------------------------------------------------------------- bucket gather + ReLU
// One block per bucket (64 nodes). LDS counting-sort of edge indices by local
// dst, then per-node register accumulation (wave per node, lane = column) with
// 4-deep MLP on the h-row gathers. No atomics on the edge path.
__global__ __launch_bounds__(256) void bgather_kernel(const __bf16* __restrict__ h,
                                                      const int2* __restrict__ payload,
                                                      const int* __restrict__ bbase,
                                                      float* __restrict__ out, int N) {
    __shared__ unsigned short sidx[CAP];   // 8 KB
    __shared__ int cnt[BNODES];
    __shared__ int off[BNODES + 1];
    const int t = threadIdx.x;
    const int wv = t >> 6, lane = t & 63;

    const int b = bbase[blockIdx.x];
    const int e = bbase[blockIdx.x + 1];
    const int m = min(e - b, CAP);         // LDS-sorted portion; tail handled below

    if (t < BNODES) cnt[t] = 0;
    __syncthreads();

    // phase A: histogram of local dst over the sorted portion
    for (int i = t; i < m; i += 256) {
        int ld = ((unsigned)payload[b + i].x) >> 25;
        atomicAdd(&cnt[ld], 1);
    }
    __syncthreads();

    // scan cnt -> off (Hillis-Steele over 64 by threads 0..63)
    if (t == 0) off[0] = 0;
    if (t < BNODES) off[t + 1] = cnt[t];
    __syncthreads();
    for (int o = 1; o < BNODES; o <<= 1) {
        int v = (t < BNODES && t >= o) ? off[t + 1 - o] : 0;
        __syncthreads();
        if (t < BNODES) off[t + 1] += v;
        __syncthreads();
    }
    if (t < BNODES) cnt[t] = 0;
    __syncthreads();

    // phase B: scatter edge indices by local dst
    for (int i = t; i < m; i += 256) {
        int ld = ((unsigned)payload[b + i].x) >> 25;
        int p = off[ld] + atomicAdd(&cnt[ld], 1);
        sidx[p] = (unsigned short)i;
    }
    __syncthreads();

    // phase C: per-node register accumulation
    const int node0 = blockIdx.x << LOGB;
    for (int nn = wv; nn < BNODES; nn += 4) {
        const int g = node0 + nn;
        if (g >= N) break;
        int i = off[nn];
        const int sE = off[nn + 1];
        float a0 = 0.f, a1 = 0.f, a2 = 0.f, a3 = 0.f;
        for (; i + 4 <= sE; i += 4) {
            int i0 = sidx[i + 0], i1 = sidx[i + 1], i2 = sidx[i + 2], i3 = sidx[i + 3];
            int2 p0 = payload[b + i0];
            int2 p1 = payload[b + i1];
            int2 p2 = payload[b + i2];
            int2 p3 = payload[b + i3];
            float h0 = (float)h[(size_t)(p0.x & 0x1FFFFFF) * OUT_F + lane];
            float h1 = (float)h[(size_t)(p1.x & 0x1FFFFFF) * OUT_F + lane];
            float h2 = (float)h[(size_t)(p2.x & 0x1FFFFFF) * OUT_F + lane];
            float h3 = (float)h[(size_t)(p3.x & 0x1FFFFFF) * OUT_F + lane];
            a0 = fmaf(h0, __int_as_float(p0.y), a0);
            a1 = fmaf(h1, __int_as_float(p1.y), a1);
            a2 = fmaf(h2, __int_as_float(p2.y), a2);
            a3 = fmaf(h3, __int_as_float(p3.y), a3);
        }
        for (; i < sE; ++i) {
            int2 p = payload[b + sidx[i]];
            a0 = fmaf((float)h[(size_t)(p.x & 0x1FFFFFF) * OUT_F + lane],
                      __int_as_float(p.y), a0);
        }
        // correct tail for buckets overflowing CAP (never for this input)
        for (int j = b + CAP; j < e; ++j) {
            int2 p = payload[j];
            if ((int)(((unsigned)p.x) >> 25) == nn)
                a0 = fmaf((float)h[(size_t)(p.x & 0x1FFFFFF) * OUT_F + lane],
                          __int_as_float(p.y), a0);
        }
        out[(size_t)g * OUT_F + lane] = fmaxf((a0 + a1) + (a2 + a3), 0.f);
    }
}

// ---------------------------------------------------------------- launch
extern "C" void kernel_launch(void* const* d_in, const int* in_sizes, int n_in,
                              void* d_out, int out_size, void* d_ws, size_t ws_size,
                              hipStream_t stream) {
    const float* feat = (const float*)d_in[0];
    const float* W    = (const float*)d_in[1];
    const float* ew   = (const float*)d_in[2];
    const int*   src  = (const int*)d_in[3];
    const int*   dst  = (const int*)d_in[4];
    float* out = (float*)d_out;

    const int N = in_sizes[0] / IN_F;
    const int E = in_sizes[2];
    const int nbuck = (N + BNODES - 1) >> LOGB;

    // workspace layout (payload first to keep int2 8B-aligned)
    char* ws = (char*)d_ws;
    int2*   payload = (int2*)ws;   ws += (size_t)E * 8;            // 12.8 MB
    __bf16* h       = (__bf16*)ws; ws += (size_t)N * OUT_F * 2;    // 12.8 MB
    __bf16* wfrag   = (__bf16*)ws; ws += 32 * 64 * 8 * 2;          // 32 KB
    int*    bcnt    = (int*)ws;    ws += (MAXBUCK + 1) * 4;
    int*    bbase   = (int*)ws;    ws += (MAXBUCK + 1) * 4;
    int*    bcursor = (int*)ws;                                    // MAXBUCK

    hipMemsetAsync(bcnt, 0, (size_t)nbuck * 4, stream);

    hipLaunchKernelGGL(wfrag_kernel, dim3(32), dim3(64), 0, stream, W, wfrag);
    hipLaunchKernelGGL(gemm_mfma_kernel, dim3((N + 63) / 64), dim3(256), 0, stream, feat, wfrag, h, N);
    hipLaunchKernelGGL(bhist_kernel, dim3(512), dim3(256), 0, stream, dst, bcnt, E, nbuck);
    hipLaunchKernelGGL(bscan_kernel, dim3(1), dim3(1024), 0, stream, bcnt, bbase, bcursor, nbuck);
    hipLaunchKernelGGL(bscatter_kernel, dim3((E + 4095) / 4096), dim3(1024), 0, stream,
                       src, dst, ew, bcursor, payload, E, nbuck);
    hipLaunchKernelGGL(bgather_kernel, dim3(nbuck), dim3(256), 0, stream, h, payload, bbase, out, N);
}

// Round 8
// 150.527 us; speedup vs baseline: 5.0262x; 1.1223x over previous
//
#include <hip/hip_runtime.h>

#define IN_F 256
#define OUT_F 64
#define LOGB 5            // 32 nodes per bucket
#define BNODES 32
#define MAXBUCK 4096      // supports N <= 131072
#define CAP 2048          // sorted edges per bucket (4x mean); tail handled correctly

typedef __bf16 bf16x8 __attribute__((ext_vector_type(8)));
typedef float f32x4 __attribute__((ext_vector_type(4)));

// ---------------------------------------------------------------- W fragment prep
__global__ __launch_bounds__(64) void wfrag_kernel(const float* __restrict__ W,
                                                   __bf16* __restrict__ wfrag) {
    const int st = blockIdx.x;
    const int s = st >> 2, t = st & 3;
    const int l = threadIdx.x;
    const int n = t * 16 + (l & 15);
    const int k0 = s * 32 + (l >> 4) * 8;
    bf16x8 f;
#pragma unroll
    for (int j = 0; j < 8; ++j)
        f[j] = (__bf16)W[(k0 + j) * OUT_F + n];
    *(bf16x8*)(wfrag + (size_t)(st * 64 + l) * 8) = f;
}

// ---------------------------------------------------------------- MFMA GEMM h = feat @ W (bf16 out)
__global__ __launch_bounds__(256) void gemm_mfma_kernel(const float* __restrict__ feat,
                                                        const __bf16* __restrict__ wfrag,
                                                        __bf16* __restrict__ h, int N) {
    const int tid = threadIdx.x;
    const int wv = tid >> 6;
    const int l = tid & 63;
    const int m0 = blockIdx.x * 64 + wv * 16;
    const int q = l >> 4;
    const int row = min(m0 + (l & 15), N - 1);

    const float* __restrict__ arow = feat + (size_t)row * IN_F + q * 8;
    const bf16x8* __restrict__ wf = (const bf16x8*)wfrag; // [32 frags][64 lanes]

    f32x4 acc0 = {0.f, 0.f, 0.f, 0.f};
    f32x4 acc1 = {0.f, 0.f, 0.f, 0.f};
    f32x4 acc2 = {0.f, 0.f, 0.f, 0.f};
    f32x4 acc3 = {0.f, 0.f, 0.f, 0.f};

#pragma unroll
    for (int s = 0; s < 8; ++s) {
        float4 fa0 = *(const float4*)(arow + s * 32);
        float4 fa1 = *(const float4*)(arow + s * 32 + 4);
        bf16x8 a;
        a[0] = (__bf16)fa0.x; a[1] = (__bf16)fa0.y;
        a[2] = (__bf16)fa0.z; a[3] = (__bf16)fa0.w;
        a[4] = (__bf16)fa1.x; a[5] = (__bf16)fa1.y;
        a[6] = (__bf16)fa1.z; a[7] = (__bf16)fa1.w;
        bf16x8 b0 = wf[(s * 4 + 0) * 64 + l];
        bf16x8 b1 = wf[(s * 4 + 1) * 64 + l];
        bf16x8 b2 = wf[(s * 4 + 2) * 64 + l];
        bf16x8 b3 = wf[(s * 4 + 3) * 64 + l];
        acc0 = __builtin_amdgcn_mfma_f32_16x16x32_bf16(a, b0, acc0, 0, 0, 0);
        acc1 = __builtin_amdgcn_mfma_f32_16x16x32_bf16(a, b1, acc1, 0, 0, 0);
        acc2 = __builtin_amdgcn_mfma_f32_16x16x32_bf16(a, b2, acc2, 0, 0, 0);
        acc3 = __builtin_amdgcn_mfma_f32_16x16x32_bf16(a, b3, acc3, 0, 0, 0);
    }

    const int colb = l & 15;
#pragma unroll
    for (int r = 0; r < 4; ++r) {
        int ro = m0 + q * 4 + r;
        if (ro < N) {
            __bf16* hp = h + (size_t)ro * OUT_F + colb;
            hp[0]  = (__bf16)acc0[r];
            hp[16] = (__bf16)acc1[r];
            hp[32] = (__bf16)acc2[r];
            hp[48] = (__bf16)acc3[r];
        }
    }
}

// ---------------------------------------------------------------- bucket histogram
__global__ __launch_bounds__(256) void bhist_kernel(const int* __restrict__ dst,
                                                    int* __restrict__ bcnt, int E, int nbuck) {
    __shared__ int hist[MAXBUCK];
    for (int i = threadIdx.x; i < nbuck; i += 256) hist[i] = 0;
    __syncthreads();
    const int stride = gridDim.x * 1024;
    for (int base = (blockIdx.x * 256 + threadIdx.x) * 4; base < E; base += stride) {
        if (base + 4 <= E) {
            int4 d4 = *(const int4*)(dst + base);
            atomicAdd(&hist[d4.x >> LOGB], 1);
            atomicAdd(&hist[d4.y >> LOGB], 1);
            atomicAdd(&hist[d4.z >> LOGB], 1);
            atomicAdd(&hist[d4.w >> LOGB], 1);
        } else {
            for (int e = base; e < E; ++e) atomicAdd(&hist[dst[e] >> LOGB], 1);
        }
    }
    __syncthreads();
    for (int i = threadIdx.x; i < nbuck; i += 256)
        if (hist[i]) atomicAdd(&bcnt[i], hist[i]);
}

// ---------------------------------------------------------------- bucket scan (1 block, nbuck <= 4096)
__global__ __launch_bounds__(1024) void bscan_kernel(const int* __restrict__ bcnt,
                                                     int* __restrict__ bbase,
                                                     int* __restrict__ bcursor, int nbuck) {
    __shared__ int s[1024];
    const int t = threadIdx.x;
    int v[4];
    int sum = 0;
#pragma unroll
    for (int j = 0; j < 4; ++j) {
        int i = 4 * t + j;
        v[j] = (i < nbuck) ? bcnt[i] : 0;
        sum += v[j];
    }
    s[t] = sum;
    __syncthreads();
    for (int o = 1; o < 1024; o <<= 1) {
        int x = (t >= o) ? s[t - o] : 0;
        __syncthreads();
        s[t] += x;
        __syncthreads();
    }
    int ex = s[t] - sum;
#pragma unroll
    for (int j = 0; j < 4; ++j) {
        int i = 4 * t + j;
        if (i < nbuck) { bbase[i] = ex; bcursor[i] = ex; }
        ex += v[j];
    }
    if (t == 1023) bbase[nbuck] = s[1023];
}

// ---------------------------------------------------------------- bucket scatter
__global__ __launch_bounds__(1024) void bscatter_kernel(const int* __restrict__ src,
                                                        const int* __restrict__ dst,
                                                        const float* __restrict__ ew,
                                                        int* __restrict__ bcursor,
                                                        int2* __restrict__ payload,
                                                        int E, int nbuck) {
    __shared__ int cnt[MAXBUCK];
    __shared__ int basearr[MAXBUCK];
    const int t = threadIdx.x;
    for (int i = t; i < nbuck; i += 1024) cnt[i] = 0;
    __syncthreads();

    const int base = (blockIdx.x * 1024 + t) * 4;
    int dd[4] = {0, 0, 0, 0}, ss[4] = {0, 0, 0, 0};
    float ww[4] = {0.f, 0.f, 0.f, 0.f};
    int nv = 0;
    if (base + 4 <= E) {
        int4 d4 = *(const int4*)(dst + base);
        int4 s4 = *(const int4*)(src + base);
        float4 w4 = *(const float4*)(ew + base);
        dd[0] = d4.x; dd[1] = d4.y; dd[2] = d4.z; dd[3] = d4.w;
        ss[0] = s4.x; ss[1] = s4.y; ss[2] = s4.z; ss[3] = s4.w;
        ww[0] = w4.x; ww[1] = w4.y; ww[2] = w4.z; ww[3] = w4.w;
        nv = 4;
    } else if (base < E) {
        nv = E - base;
#pragma unroll 4
        for (int j = 0; j < 4; ++j)
            if (j < nv) { dd[j] = dst[base + j]; ss[j] = src[base + j]; ww[j] = ew[base + j]; }
    }

    int idx[4];
#pragma unroll 4
    for (int j = 0; j < 4; ++j)
        if (j < nv) idx[j] = atomicAdd(&cnt[dd[j] >> LOGB], 1);
    __syncthreads();

    for (int i = t; i < nbuck; i += 1024)
        if (cnt[i]) basearr[i] = atomicAdd(&bcursor[i], cnt[i]);
    __syncthreads();

#pragma unroll 4
    for (int j = 0; j < 4; ++j)
        if (j < nv) {
            int pos = basearr[dd[j] >> LOGB] + idx[j];
            payload[pos] = make_int2(ss[j] | ((dd[j] & (BNODES - 1)) << 25),
                                     __float_as_int(ww[j]));
        }
}

// ---------------------------------------------------------------- bucket gather + ReLU
// One block per bucket (32 nodes). LDS counting-sort of edge indices by local
// dst, then per-node register accumulation: lane l handles column pair
// (2j, 2j+1), j = l&31; half-wave 0 takes even edges, half-wave 1 odd edges of
// the same node; one uint load = 2 bf16 = 2 edges per VMEM instruction.
__global__ __launch_bounds__(256) void bgather_kernel(const __bf16* __restrict__ h,
                                                      const int2* __restrict__ payload,
                                                      const int* __restrict__ bbase,
                                                      float* __restrict__ out, int N) {
    __shared__ unsigned short sidx[CAP];   // 4 KB
    __shared__ int cnt[BNODES];
    __shared__ int off[BNODES + 1];
    const int t = threadIdx.x;
    const int wv = t >> 6;
    const int l = t & 63;
    const int half = l >> 5;       // 0: even edges, 1: odd edges
    const int j = l & 31;          // column pair index

    const int b = bbase[blockIdx.x];
    const int e = bbase[blockIdx.x + 1];
    const int m = min(e - b, CAP); // LDS-sorted portion; overflow tail below

    if (t < BNODES) cnt[t] = 0;
    __syncthreads();

    // phase A: histogram of local dst
    for (int i = t; i < m; i += 256)
        atomicAdd(&cnt[((unsigned)payload[b + i].x) >> 25], 1);
    __syncthreads();

    // scan cnt -> off
    if (t == 0) off[0] = 0;
    if (t < BNODES) off[t + 1] = cnt[t];
    __syncthreads();
    for (int o = 1; o < BNODES; o <<= 1) {
        int v = (t < BNODES && t >= o) ? off[t + 1 - o] : 0;
        __syncthreads();
        if (t < BNODES) off[t + 1] += v;
        __syncthreads();
    }
    if (t < BNODES) cnt[t] = 0;
    __syncthreads();

    // phase B: scatter edge indices by local dst
    for (int i = t; i < m; i += 256) {
        int ld = ((unsigned)payload[b + i].x) >> 25;
        int p = off[ld] + atomicAdd(&cnt[ld], 1);
        sidx[p] = (unsigned short)i;
    }
    __syncthreads();

    // phase C: per-node accumulation, 2 cols/lane, half-wave edge pairing
    const unsigned* __restrict__ h32 = (const unsigned*)h;
    const int node0 = blockIdx.x << LOGB;
    for (int nn = wv; nn < BNODES; nn += 4) {
        const int g = node0 + nn;
        if (g >= N) break;
        int i = off[nn];
        const int sE = off[nn + 1];
        float a0A = 0.f, a0B = 0.f, a1A = 0.f, a1B = 0.f;
        for (; i + 8 <= sE; i += 8) {
            int e0 = sidx[i + 0 + half];
            int e1 = sidx[i + 2 + half];
            int e2 = sidx[i + 4 + half];
            int e3 = sidx[i + 6 + half];
            int2 p0 = payload[b + e0];
            int2 p1 = payload[b + e1];
            int2 p2 = payload[b + e2];
            int2 p3 = payload[b + e3];
            unsigned v0 = h32[(size_t)(p0.x & 0x1FFFFFF) * 32 + j];
            unsigned v1 = h32[(size_t)(p1.x & 0x1FFFFFF) * 32 + j];
            unsigned v2 = h32[(size_t)(p2.x & 0x1FFFFFF) * 32 + j];
            unsigned v3 = h32[(size_t)(p3.x & 0x1FFFFFF) * 32 + j];
            float w0 = __int_as_float(p0.y), w1 = __int_as_float(p1.y);
            float w2 = __int_as_float(p2.y), w3 = __int_as_float(p3.y);
            a0A = fmaf(__uint_as_float(v0 << 16), w0, a0A);
            a0B = fmaf(__uint_as_float(v0 & 0xFFFF0000u), w0, a0B);
            a1A = fmaf(__uint_as_float(v1 << 16), w1, a1A);
            a1B = fmaf(__uint_as_float(v1 & 0xFFFF0000u), w1, a1B);
            a0A = fmaf(__uint_as_float(v2 << 16), w2, a0A);
            a0B = fmaf(__uint_as_float(v2 & 0xFFFF0000u), w2, a0B);
            a1A = fmaf(__uint_as_float(v3 << 16), w3, a1A);
            a1B = fmaf(__uint_as_float(v3 & 0xFFFF0000u), w3, a1B);
        }
        for (; i + 2 <= sE; i += 2) {
            int e0 = sidx[i + half];
            int2 p0 = payload[b + e0];
            unsigned v0 = h32[(size_t)(p0.x & 0x1FFFFFF) * 32 + j];
            float w0 = __int_as_float(p0.y);
            a0A = fmaf(__uint_as_float(v0 << 16), w0, a0A);
            a0B = fmaf(__uint_as_float(v0 & 0xFFFF0000u), w0, a0B);
        }
        if (i < sE && half == 0) {        // last odd edge: half 0 only
            int e0 = sidx[i];
            int2 p0 = payload[b + e0];
            unsigned v0 = h32[(size_t)(p0.x & 0x1FFFFFF) * 32 + j];
            float w0 = __int_as_float(p0.y);
            a0A = fmaf(__uint_as_float(v0 << 16), w0, a0A);
            a0B = fmaf(__uint_as_float(v0 & 0xFFFF0000u), w0, a0B);
        }
        if (half == 0)                    // CAP overflow tail (never for this input)
            for (int q = b + CAP; q < e; ++q) {
                int2 p = payload[q];
                if ((int)(((unsigned)p.x) >> 25) == nn) {
                    unsigned v0 = h32[(size_t)(p.x & 0x1FFFFFF) * 32 + j];
                    float w0 = __int_as_float(p.y);
                    a0A = fmaf(__uint_as_float(v0 << 16), w0, a0A);
                    a0B = fmaf(__uint_as_float(v0 & 0xFFFF0000u), w0, a0B);
                }
            }
        float accA = a0A + a1A;
        float accB = a0B + a1B;
        accA += __shfl_xor(accA, 32);
        accB += __shfl_xor(accB, 32);
        if (half == 0) {
            float2 v;
            v.x = fmaxf(accA, 0.f);
            v.y = fmaxf(accB, 0.f);
            *(float2*)(out + (size_t)g * OUT_F + 2 * j) = v;
        }
    }
}

// ---------------------------------------------------------------- launch
extern "C" void kernel_launch(void* const* d_in, const int* in_sizes, int n_in,
                              void* d_out, int out_size, void* d_ws, size_t ws_size,
                              hipStream_t stream) {
    const float* feat = (const float*)d_in[0];
    const float* W    = (const float*)d_in[1];
    const float* ew   = (const float*)d_in[2];
    const int*   src  = (const int*)d_in[3];
    const int*   dst  = (const int*)d_in[4];
    float* out = (float*)d_out;

    const int N = in_sizes[0] / IN_F;
    const int E = in_sizes[2];
    const int nbuck = (N + BNODES - 1) >> LOGB;

    // workspace layout (payload first to keep int2 8B-aligned)
    char* ws = (char*)d_ws;
    int2*   payload = (int2*)ws;   ws += (size_t)E * 8;            // 12.8 MB
    __bf16* h       = (__bf16*)ws; ws += (size_t)N * OUT_F * 2;    // 12.8 MB
    __bf16* wfrag   = (__bf16*)ws; ws += 32 * 64 * 8 * 2;          // 32 KB
    int*    bcnt    = (int*)ws;    ws += (MAXBUCK + 1) * 4;
    int*    bbase   = (int*)ws;    ws += (MAXBUCK + 1) * 4;
    int*    bcursor = (int*)ws;                                    // MAXBUCK

    hipMemsetAsync(bcnt, 0, (size_t)nbuck * 4, stream);

    hipLaunchKernelGGL(wfrag_kernel, dim3(32), dim3(64), 0, stream, W, wfrag);
    hipLaunchKernelGGL(gemm_mfma_kernel, dim3((N + 63) / 64), dim3(256), 0, stream, feat, wfrag, h, N);
    hipLaunchKernelGGL(bhist_kernel, dim3(512), dim3(256), 0, stream, dst, bcnt, E, nbuck);
    hipLaunchKernelGGL(bscan_kernel, dim3(1), dim3(1024), 0, stream, bcnt, bbase, bcursor, nbuck);
    hipLaunchKernelGGL(bscatter_kernel, dim3((E + 4095) / 4096), dim3(1024), 0, stream,
                       src, dst, ew, bcursor, payload, E, nbuck);
    hipLaunchKernelGGL(bgather_kernel, dim3(nbuck), dim3(256), 0, stream, h, payload, bbase, out, N);
}

// Round 9
// 145.074 us; speedup vs baseline: 5.2151x; 1.0376x over previous
//
#include <hip/hip_runtime.h>

#define IN_F 256
#define OUT_F 64
#define LOGSB 8           // 256 nodes per super-bucket
#define SBNODES 256
#define MAXSB 1024        // supports N <= 262144

typedef __bf16 bf16x8 __attribute__((ext_vector_type(8)));
typedef float f32x4 __attribute__((ext_vector_type(4)));

// ---------------------------------------------------------------- W fragment prep
__global__ __launch_bounds__(64) void wfrag_kernel(const float* __restrict__ W,
                                                   __bf16* __restrict__ wfrag) {
    const int st = blockIdx.x;
    const int s = st >> 2, t = st & 3;
    const int l = threadIdx.x;
    const int n = t * 16 + (l & 15);
    const int k0 = s * 32 + (l >> 4) * 8;
    bf16x8 f;
#pragma unroll
    for (int j = 0; j < 8; ++j)
        f[j] = (__bf16)W[(k0 + j) * OUT_F + n];
    *(bf16x8*)(wfrag + (size_t)(st * 64 + l) * 8) = f;
}

// ---------------------------------------------------------------- MFMA GEMM h = feat @ W (bf16 out)
__global__ __launch_bounds__(256) void gemm_mfma_kernel(const float* __restrict__ feat,
                                                        const __bf16* __restrict__ wfrag,
                                                        __bf16* __restrict__ h, int N) {
    const int tid = threadIdx.x;
    const int wv = tid >> 6;
    const int l = tid & 63;
    const int m0 = blockIdx.x * 64 + wv * 16;
    const int q = l >> 4;
    const int row = min(m0 + (l & 15), N - 1);

    const float* __restrict__ arow = feat + (size_t)row * IN_F + q * 8;
    const bf16x8* __restrict__ wf = (const bf16x8*)wfrag; // [32 frags][64 lanes]

    f32x4 acc0 = {0.f, 0.f, 0.f, 0.f};
    f32x4 acc1 = {0.f, 0.f, 0.f, 0.f};
    f32x4 acc2 = {0.f, 0.f, 0.f, 0.f};
    f32x4 acc3 = {0.f, 0.f, 0.f, 0.f};

#pragma unroll
    for (int s = 0; s < 8; ++s) {
        float4 fa0 = *(const float4*)(arow + s * 32);
        float4 fa1 = *(const float4*)(arow + s * 32 + 4);
        bf16x8 a;
        a[0] = (__bf16)fa0.x; a[1] = (__bf16)fa0.y;
        a[2] = (__bf16)fa0.z; a[3] = (__bf16)fa0.w;
        a[4] = (__bf16)fa1.x; a[5] = (__bf16)fa1.y;
        a[6] = (__bf16)fa1.z; a[7] = (__bf16)fa1.w;
        bf16x8 b0 = wf[(s * 4 + 0) * 64 + l];
        bf16x8 b1 = wf[(s * 4 + 1) * 64 + l];
        bf16x8 b2 = wf[(s * 4 + 2) * 64 + l];
        bf16x8 b3 = wf[(s * 4 + 3) * 64 + l];
        acc0 = __builtin_amdgcn_mfma_f32_16x16x32_bf16(a, b0, acc0, 0, 0, 0);
        acc1 = __builtin_amdgcn_mfma_f32_16x16x32_bf16(a, b1, acc1, 0, 0, 0);
        acc2 = __builtin_amdgcn_mfma_f32_16x16x32_bf16(a, b2, acc2, 0, 0, 0);
        acc3 = __builtin_amdgcn_mfma_f32_16x16x32_bf16(a, b3, acc3, 0, 0, 0);
    }

    const int colb = l & 15;
#pragma unroll
    for (int r = 0; r < 4; ++r) {
        int ro = m0 + q * 4 + r;
        if (ro < N) {
            __bf16* hp = h + (size_t)ro * OUT_F + colb;
            hp[0]  = (__bf16)acc0[r];
            hp[16] = (__bf16)acc1[r];
            hp[32] = (__bf16)acc2[r];
            hp[48] = (__bf16)acc3[r];
        }
    }
}

// ---------------------------------------------------------------- super-bucket histogram
__global__ __launch_bounds__(256) void sbhist_kernel(const int* __restrict__ dst,
                                                     int* __restrict__ bcnt, int E, int nsb) {
    __shared__ int hist[MAXSB];
    for (int i = threadIdx.x; i < nsb; i += 256) hist[i] = 0;
    __syncthreads();
    const int stride = gridDim.x * 1024;
    for (int base = (blockIdx.x * 256 + threadIdx.x) * 4; base < E; base += stride) {
        if (base + 4 <= E) {
            int4 d4 = *(const int4*)(dst + base);
            atomicAdd(&hist[d4.x >> LOGSB], 1);
            atomicAdd(&hist[d4.y >> LOGSB], 1);
            atomicAdd(&hist[d4.z >> LOGSB], 1);
            atomicAdd(&hist[d4.w >> LOGSB], 1);
        } else {
            for (int e = base; e < E; ++e) atomicAdd(&hist[dst[e] >> LOGSB], 1);
        }
    }
    __syncthreads();
    for (int i = threadIdx.x; i < nsb; i += 256)
        if (hist[i]) atomicAdd(&bcnt[i], hist[i]);
}

// ---------------------------------------------------------------- super-bucket scan (1 block, nsb <= 1024)
__global__ __launch_bounds__(1024) void sbscan_kernel(const int* __restrict__ bcnt,
                                                      int* __restrict__ sbbase,
                                                      int* __restrict__ sbcur,
                                                      int* __restrict__ noff,
                                                      int nsb, int N, int E) {
    __shared__ int s[1024];
    const int t = threadIdx.x;
    int v = (t < nsb) ? bcnt[t] : 0;
    s[t] = v;
    __syncthreads();
    for (int o = 1; o < 1024; o <<= 1) {
        int x = (t >= o) ? s[t - o] : 0;
        __syncthreads();
        s[t] += x;
        __syncthreads();
    }
    if (t < nsb) {
        int ex = s[t] - v;
        sbbase[t] = ex;
        sbcur[t] = ex;
    }
    if (t == 0) {
        sbbase[nsb] = E;
        noff[N] = E;   // global sentinel
    }
}

// ---------------------------------------------------------------- super-bucket scatter
// Packs local node id (dst & 255) into src bits 24..31.
__global__ __launch_bounds__(1024) void sbscatter_kernel(const int* __restrict__ src,
                                                         const int* __restrict__ dst,
                                                         const float* __restrict__ ew,
                                                         int* __restrict__ sbcur,
                                                         int2* __restrict__ payload,
                                                         int E, int nsb) {
    __shared__ int cnt[MAXSB];
    __shared__ int basearr[MAXSB];
    const int t = threadIdx.x;
    for (int i = t; i < nsb; i += 1024) cnt[i] = 0;
    __syncthreads();

    const int base = (blockIdx.x * 1024 + t) * 4;
    int dd[4] = {0, 0, 0, 0}, ss[4] = {0, 0, 0, 0};
    float ww[4] = {0.f, 0.f, 0.f, 0.f};
    int nv = 0;
    if (base + 4 <= E) {
        int4 d4 = *(const int4*)(dst + base);
        int4 s4 = *(const int4*)(src + base);
        float4 w4 = *(const float4*)(ew + base);
        dd[0] = d4.x; dd[1] = d4.y; dd[2] = d4.z; dd[3] = d4.w;
        ss[0] = s4.x; ss[1] = s4.y; ss[2] = s4.z; ss[3] = s4.w;
        ww[0] = w4.x; ww[1] = w4.y; ww[2] = w4.z; ww[3] = w4.w;
        nv = 4;
    } else if (base < E) {
        nv = E - base;
#pragma unroll 4
        for (int j = 0; j < 4; ++j)
            if (j < nv) { dd[j] = dst[base + j]; ss[j] = src[base + j]; ww[j] = ew[base + j]; }
    }

    int idx[4];
#pragma unroll 4
    for (int j = 0; j < 4; ++j)
        if (j < nv) idx[j] = atomicAdd(&cnt[dd[j] >> LOGSB], 1);
    __syncthreads();

    for (int i = t; i < nsb; i += 1024)
        if (cnt[i]) basearr[i] = atomicAdd(&sbcur[i], cnt[i]);
    __syncthreads();

#pragma unroll 4
    for (int j = 0; j < 4; ++j)
        if (j < nv) {
            int pos = basearr[dd[j] >> LOGSB] + idx[j];
            payload[pos] = make_int2(ss[j] | ((dd[j] & (SBNODES - 1)) << 24),
                                     __float_as_int(ww[j]));
        }
}

// ---------------------------------------------------------------- fine sort within super-bucket
// One block per super-bucket: counting-sort its edges by local node into
// payload2 (node-sorted, src-only), write absolute per-node offsets noff[g].
// All writes land in the SB's own ~32 KB region -> L2-resident, dense writeback.
__global__ __launch_bounds__(256) void fsort_kernel(const int2* __restrict__ payload,
                                                    int2* __restrict__ payload2,
                                                    const int* __restrict__ sbbase,
                                                    int* __restrict__ noff, int N) {
    __shared__ int cnt[SBNODES];
    __shared__ int off[SBNODES + 1];
    __shared__ int tick[SBNODES];
    const int t = threadIdx.x;
    const int b = sbbase[blockIdx.x];
    const int e = sbbase[blockIdx.x + 1];
    const int m = e - b;

    cnt[t] = 0;
    __syncthreads();
    for (int i = t; i < m; i += 256)
        atomicAdd(&cnt[((unsigned)payload[b + i].x) >> 24], 1);
    __syncthreads();

    if (t == 0) off[0] = 0;
    off[t + 1] = cnt[t];
    __syncthreads();
    for (int o = 1; o < SBNODES; o <<= 1) {
        int v = (t >= o) ? off[t + 1 - o] : 0;
        __syncthreads();
        off[t + 1] += v;
        __syncthreads();
    }

    const int g = (blockIdx.x << LOGSB) + t;
    if (g < N) noff[g] = b + off[t];
    tick[t] = 0;
    __syncthreads();

    for (int i = t; i < m; i += 256) {
        int2 p = payload[b + i];
        int ld = ((unsigned)p.x) >> 24;
        int pos = b + off[ld] + atomicAdd(&tick[ld], 1);
        payload2[pos] = make_int2(p.x & 0xFFFFFF, p.y);
    }
}

// ---------------------------------------------------------------- gather + ReLU (no LDS, no sort)
// Grid (N+31)/32; wave wv owns 8 consecutive nodes. Lane l: column pair
// (2j,2j+1), j=l&31; half-wave 0 even edges, half-wave 1 odd edges. Payload
// segments are node-contiguous (from fsort).
__global__ __launch_bounds__(256) void bgather_kernel(const __bf16* __restrict__ h,
                                                      const int2* __restrict__ payload2,
                                                      const int* __restrict__ noff,
                                                      float* __restrict__ out, int N) {
    const int t = threadIdx.x;
    const int wv = t >> 6;
    const int l = t & 63;
    const int half = l >> 5;
    const int j = l & 31;
    const unsigned* __restrict__ h32 = (const unsigned*)h;
    const int g0 = blockIdx.x * 32 + wv * 8;

#pragma unroll 1
    for (int k = 0; k < 8; ++k) {
        const int g = g0 + k;
        if (g >= N) return;
        int i = noff[g];
        const int eE = noff[g + 1];
        float a0A = 0.f, a0B = 0.f, a1A = 0.f, a1B = 0.f;
        for (; i + 8 <= eE; i += 8) {
            int2 p0 = payload2[i + 0 + half];
            int2 p1 = payload2[i + 2 + half];
            int2 p2 = payload2[i + 4 + half];
            int2 p3 = payload2[i + 6 + half];
            unsigned v0 = h32[(size_t)p0.x * 32 + j];
            unsigned v1 = h32[(size_t)p1.x * 32 + j];
            unsigned v2 = h32[(size_t)p2.x * 32 + j];
            unsigned v3 = h32[(size_t)p3.x * 32 + j];
            float w0 = __int_as_float(p0.y), w1 = __int_as_float(p1.y);
            float w2 = __int_as_float(p2.y), w3 = __int_as_float(p3.y);
            a0A = fmaf(__uint_as_float(v0 << 16), w0, a0A);
            a0B = fmaf(__uint_as_float(v0 & 0xFFFF0000u), w0, a0B);
            a1A = fmaf(__uint_as_float(v1 << 16), w1, a1A);
            a1B = fmaf(__uint_as_float(v1 & 0xFFFF0000u), w1, a1B);
            a0A = fmaf(__uint_as_float(v2 << 16), w2, a0A);
            a0B = fmaf(__uint_as_float(v2 & 0xFFFF0000u), w2, a0B);
            a1A = fmaf(__uint_as_float(v3 << 16), w3, a1A);
            a1B = fmaf(__uint_as_float(v3 & 0xFFFF0000u), w3, a1B);
        }
        for (; i + 2 <= eE; i += 2) {
            int2 p0 = payload2[i + half];
            unsigned v0 = h32[(size_t)p0.x * 32 + j];
            float w0 = __int_as_float(p0.y);
            a0A = fmaf(__uint_as_float(v0 << 16), w0, a0A);
            a0B = fmaf(__uint_as_float(v0 & 0xFFFF0000u), w0, a0B);
        }
        if (i < eE && half == 0) {
            int2 p0 = payload2[i];
            unsigned v0 = h32[(size_t)p0.x * 32 + j];
            float w0 = __int_as_float(p0.y);
            a0A = fmaf(__uint_as_float(v0 << 16), w0, a0A);
            a0B = fmaf(__uint_as_float(v0 & 0xFFFF0000u), w0, a0B);
        }
        float accA = a0A + a1A;
        float accB = a0B + a1B;
        accA += __shfl_xor(accA, 32);
        accB += __shfl_xor(accB, 32);
        if (half == 0) {
            float2 v;
            v.x = fmaxf(accA, 0.f);
            v.y = fmaxf(accB, 0.f);
            *(float2*)(out + (size_t)g * OUT_F + 2 * j) = v;
        }
    }
}

// ---------------------------------------------------------------- launch
extern "C" void kernel_launch(void* const* d_in, const int* in_sizes, int n_in,
                              void* d_out, int out_size, void* d_ws, size_t ws_size,
                              hipStream_t stream) {
    const float* feat = (const float*)d_in[0];
    const float* W    = (const float*)d_in[1];
    const float* ew   = (const float*)d_in[2];
    const int*   src  = (const int*)d_in[3];
    const int*   dst  = (const int*)d_in[4];
    float* out = (float*)d_out;

    const int N = in_sizes[0] / IN_F;
    const int E = in_sizes[2];
    const int nsb = (N + SBNODES - 1) >> LOGSB;

    // workspace layout (8B-aligned first)
    char* ws = (char*)d_ws;
    int2*   payload  = (int2*)ws;   ws += (size_t)E * 8;            // 12.8 MB
    int2*   payload2 = (int2*)ws;   ws += (size_t)E * 8;            // 12.8 MB
    __bf16* h        = (__bf16*)ws; ws += (size_t)N * OUT_F * 2;    // 12.8 MB
    __bf16* wfrag    = (__bf16*)ws; ws += 32 * 64 * 8 * 2;          // 32 KB
    int*    bcnt     = (int*)ws;    ws += (MAXSB + 1) * 4;
    int*    sbbase   = (int*)ws;    ws += (MAXSB + 1) * 4;
    int*    sbcur    = (int*)ws;    ws += MAXSB * 4;
    int*    noff     = (int*)ws;                                    // (N+1)*4 = 400 KB

    hipMemsetAsync(bcnt, 0, (size_t)nsb * 4, stream);

    hipLaunchKernelGGL(wfrag_kernel, dim3(32), dim3(64), 0, stream, W, wfrag);
    hipLaunchKernelGGL(gemm_mfma_kernel, dim3((N + 63) / 64), dim3(256), 0, stream, feat, wfrag, h, N);
    hipLaunchKernelGGL(sbhist_kernel, dim3(512), dim3(256), 0, stream, dst, bcnt, E, nsb);
    hipLaunchKernelGGL(sbscan_kernel, dim3(1), dim3(1024), 0, stream, bcnt, sbbase, sbcur, noff, nsb, N, E);
    hipLaunchKernelGGL(sbscatter_kernel, dim3((E + 4095) / 4096), dim3(1024), 0, stream,
                       src, dst, ew, sbcur, payload, E, nsb);
    hipLaunchKernelGGL(fsort_kernel, dim3(nsb), dim3(256), 0, stream, payload, payload2, sbbase, noff, N);
    hipLaunchKernelGGL(bgather_kernel, dim3((N + 31) / 32), dim3(256), 0, stream, h, payload2, noff, out, N);
}

// Round 10
// 129.122 us; speedup vs baseline: 5.8594x; 1.1235x over previous
//
#include <hip/hip_runtime.h>

#define IN_F 256
#define OUT_F 64
#define LOGSB 8           // 256 nodes per super-bucket
#define SBNODES 256
#define MAXSB 1024        // supports N <= 262144

typedef __bf16 bf16x8 __attribute__((ext_vector_type(8)));
typedef float f32x4 __attribute__((ext_vector_type(4)));

// ---------------------------------------------------------------- W fragment prep
__global__ __launch_bounds__(64) void wfrag_kernel(const float* __restrict__ W,
                                                   __bf16* __restrict__ wfrag) {
    const int st = blockIdx.x;
    const int s = st >> 2, t = st & 3;
    const int l = threadIdx.x;
    const int n = t * 16 + (l & 15);
    const int k0 = s * 32 + (l >> 4) * 8;
    bf16x8 f;
#pragma unroll
    for (int j = 0; j < 8; ++j)
        f[j] = (__bf16)W[(k0 + j) * OUT_F + n];
    *(bf16x8*)(wfrag + (size_t)(st * 64 + l) * 8) = f;
}

// ---------------------------------------------------------------- MFMA GEMM h = feat @ W (bf16 out)
__global__ __launch_bounds__(256) void gemm_mfma_kernel(const float* __restrict__ feat,
                                                        const __bf16* __restrict__ wfrag,
                                                        __bf16* __restrict__ h, int N) {
    const int tid = threadIdx.x;
    const int wv = tid >> 6;
    const int l = tid & 63;
    const int m0 = blockIdx.x * 64 + wv * 16;
    const int q = l >> 4;
    const int row = min(m0 + (l & 15), N - 1);

    const float* __restrict__ arow = feat + (size_t)row * IN_F + q * 8;
    const bf16x8* __restrict__ wf = (const bf16x8*)wfrag; // [32 frags][64 lanes]

    f32x4 acc0 = {0.f, 0.f, 0.f, 0.f};
    f32x4 acc1 = {0.f, 0.f, 0.f, 0.f};
    f32x4 acc2 = {0.f, 0.f, 0.f, 0.f};
    f32x4 acc3 = {0.f, 0.f, 0.f, 0.f};

#pragma unroll
    for (int s = 0; s < 8; ++s) {
        float4 fa0 = *(const float4*)(arow + s * 32);
        float4 fa1 = *(const float4*)(arow + s * 32 + 4);
        bf16x8 a;
        a[0] = (__bf16)fa0.x; a[1] = (__bf16)fa0.y;
        a[2] = (__bf16)fa0.z; a[3] = (__bf16)fa0.w;
        a[4] = (__bf16)fa1.x; a[5] = (__bf16)fa1.y;
        a[6] = (__bf16)fa1.z; a[7] = (__bf16)fa1.w;
        bf16x8 b0 = wf[(s * 4 + 0) * 64 + l];
        bf16x8 b1 = wf[(s * 4 + 1) * 64 + l];
        bf16x8 b2 = wf[(s * 4 + 2) * 64 + l];
        bf16x8 b3 = wf[(s * 4 + 3) * 64 + l];
        acc0 = __builtin_amdgcn_mfma_f32_16x16x32_bf16(a, b0, acc0, 0, 0, 0);
        acc1 = __builtin_amdgcn_mfma_f32_16x16x32_bf16(a, b1, acc1, 0, 0, 0);
        acc2 = __builtin_amdgcn_mfma_f32_16x16x32_bf16(a, b2, acc2, 0, 0, 0);
        acc3 = __builtin_amdgcn_mfma_f32_16x16x32_bf16(a, b3, acc3, 0, 0, 0);
    }

    const int colb = l & 15;
#pragma unroll
    for (int r = 0; r < 4; ++r) {
        int ro = m0 + q * 4 + r;
        if (ro < N) {
            __bf16* hp = h + (size_t)ro * OUT_F + colb;
            hp[0]  = (__bf16)acc0[r];
            hp[16] = (__bf16)acc1[r];
            hp[32] = (__bf16)acc2[r];
            hp[48] = (__bf16)acc3[r];
        }
    }
}

// ---------------------------------------------------------------- super-bucket histogram
__global__ __launch_bounds__(256) void sbhist_kernel(const int* __restrict__ dst,
                                                     int* __restrict__ bcnt, int E, int nsb) {
    __shared__ int hist[MAXSB];
    for (int i = threadIdx.x; i < nsb; i += 256) hist[i] = 0;
    __syncthreads();
    const int stride = gridDim.x * 1024;
    for (int base = (blockIdx.x * 256 + threadIdx.x) * 4; base < E; base += stride) {
        if (base + 4 <= E) {
            int4 d4 = *(const int4*)(dst + base);
            atomicAdd(&hist[d4.x >> LOGSB], 1);
            atomicAdd(&hist[d4.y >> LOGSB], 1);
            atomicAdd(&hist[d4.z >> LOGSB], 1);
            atomicAdd(&hist[d4.w >> LOGSB], 1);
        } else {
            for (int e = base; e < E; ++e) atomicAdd(&hist[dst[e] >> LOGSB], 1);
        }
    }
    __syncthreads();
    for (int i = threadIdx.x; i < nsb; i += 256)
        if (hist[i]) atomicAdd(&bcnt[i], hist[i]);
}

// ---------------------------------------------------------------- super-bucket scan (1 block, nsb <= 1024)
__global__ __launch_bounds__(1024) void sbscan_kernel(const int* __restrict__ bcnt,
                                                      int* __restrict__ sbbase,
                                                      int* __restrict__ sbcur,
                                                      int* __restrict__ noff,
                                                      int nsb, int N, int E) {
    __shared__ int s[1024];
    const int t = threadIdx.x;
    int v = (t < nsb) ? bcnt[t] : 0;
    s[t] = v;
    __syncthreads();
    for (int o = 1; o < 1024; o <<= 1) {
        int x = (t >= o) ? s[t - o] : 0;
        __syncthreads();
        s[t] += x;
        __syncthreads();
    }
    if (t < nsb) {
        int ex = s[t] - v;
        sbbase[t] = ex;
        sbcur[t] = ex;
    }
    if (t == 0) {
        sbbase[nsb] = E;
        noff[N] = E;   // global sentinel
    }
}

// ---------------------------------------------------------------- super-bucket scatter
// Packs local node id (dst & 255) into src bits 24..31.
__global__ __launch_bounds__(1024) void sbscatter_kernel(const int* __restrict__ src,
                                                         const int* __restrict__ dst,
                                                         const float* __restrict__ ew,
                                                         int* __restrict__ sbcur,
                                                         int2* __restrict__ payload,
                                                         int E, int nsb) {
    __shared__ int cnt[MAXSB];
    __shared__ int basearr[MAXSB];
    const int t = threadIdx.x;
    for (int i = t; i < nsb; i += 1024) cnt[i] = 0;
    __syncthreads();

    const int base = (blockIdx.x * 1024 + t) * 4;
    int dd[4] = {0, 0, 0, 0}, ss[4] = {0, 0, 0, 0};
    float ww[4] = {0.f, 0.f, 0.f, 0.f};
    int nv = 0;
    if (base + 4 <= E) {
        int4 d4 = *(const int4*)(dst + base);
        int4 s4 = *(const int4*)(src + base);
        float4 w4 = *(const float4*)(ew + base);
        dd[0] = d4.x; dd[1] = d4.y; dd[2] = d4.z; dd[3] = d4.w;
        ss[0] = s4.x; ss[1] = s4.y; ss[2] = s4.z; ss[3] = s4.w;
        ww[0] = w4.x; ww[1] = w4.y; ww[2] = w4.z; ww[3] = w4.w;
        nv = 4;
    } else if (base < E) {
        nv = E - base;
#pragma unroll 4
        for (int j = 0; j < 4; ++j)
            if (j < nv) { dd[j] = dst[base + j]; ss[j] = src[base + j]; ww[j] = ew[base + j]; }
    }

    int idx[4];
#pragma unroll 4
    for (int j = 0; j < 4; ++j)
        if (j < nv) idx[j] = atomicAdd(&cnt[dd[j] >> LOGSB], 1);
    __syncthreads();

    for (int i = t; i < nsb; i += 1024)
        if (cnt[i]) basearr[i] = atomicAdd(&sbcur[i], cnt[i]);
    __syncthreads();

#pragma unroll 4
    for (int j = 0; j < 4; ++j)
        if (j < nv) {
            int pos = basearr[dd[j] >> LOGSB] + idx[j];
            payload[pos] = make_int2(ss[j] | ((dd[j] & (SBNODES - 1)) << 24),
                                     __float_as_int(ww[j]));
        }
}

// ---------------------------------------------------------------- fine sort within super-bucket
__global__ __launch_bounds__(256) void fsort_kernel(const int2* __restrict__ payload,
                                                    int2* __restrict__ payload2,
                                                    const int* __restrict__ sbbase,
                                                    int* __restrict__ noff, int N) {
    __shared__ int cnt[SBNODES];
    __shared__ int off[SBNODES + 1];
    __shared__ int tick[SBNODES];
    const int t = threadIdx.x;
    const int b = sbbase[blockIdx.x];
    const int e = sbbase[blockIdx.x + 1];
    const int m = e - b;

    cnt[t] = 0;
    __syncthreads();
    for (int i = t; i < m; i += 256)
        atomicAdd(&cnt[((unsigned)payload[b + i].x) >> 24], 1);
    __syncthreads();

    if (t == 0) off[0] = 0;
    off[t + 1] = cnt[t];
    __syncthreads();
    for (int o = 1; o < SBNODES; o <<= 1) {
        int v = (t >= o) ? off[t + 1 - o] : 0;
        __syncthreads();
        off[t + 1] += v;
        __syncthreads();
    }

    const int g = (blockIdx.x << LOGSB) + t;
    if (g < N) noff[g] = b + off[t];
    tick[t] = 0;
    __syncthreads();

    for (int i = t; i < m; i += 256) {
        int2 p = payload[b + i];
        int ld = ((unsigned)p.x) >> 24;
        int pos = b + off[ld] + atomicAdd(&tick[ld], 1);
        payload2[pos] = make_int2(p.x & 0xFFFFFF, p.y);
    }
}

// ---------------------------------------------------------------- gather + ReLU
// Block = 256 thr = 8 half-waves; each half-wave owns its own node (4 nodes
// sequentially, stride 8). Lane j = column pair (2j, 2j+1); payload loads are
// uniform (broadcast) across the half. 8-deep main loop -> 16 VMEM in flight
// per half-wave. No cross-lane combine needed.
__global__ __launch_bounds__(256) void bgather_kernel(const __bf16* __restrict__ h,
                                                      const int2* __restrict__ payload2,
                                                      const int* __restrict__ noff,
                                                      float* __restrict__ out, int N) {
    const int t = threadIdx.x;
    const int hw = t >> 5;          // half-wave 0..7
    const int j = t & 31;           // column pair
    const unsigned* __restrict__ h32 = (const unsigned*)h;
    const int g0 = blockIdx.x * 32;

#pragma unroll 1
    for (int k = 0; k < 4; ++k) {
        const int g = g0 + hw + k * 8;
        if (g >= N) continue;
        int i = noff[g];
        const int eE = noff[g + 1];
        float a0A = 0.f, a0B = 0.f, a1A = 0.f, a1B = 0.f;
        float a2A = 0.f, a2B = 0.f, a3A = 0.f, a3B = 0.f;
        for (; i + 8 <= eE; i += 8) {
            int2 p0 = payload2[i + 0];
            int2 p1 = payload2[i + 1];
            int2 p2 = payload2[i + 2];
            int2 p3 = payload2[i + 3];
            int2 p4 = payload2[i + 4];
            int2 p5 = payload2[i + 5];
            int2 p6 = payload2[i + 6];
            int2 p7 = payload2[i + 7];
            unsigned v0 = h32[(size_t)p0.x * 32 + j];
            unsigned v1 = h32[(size_t)p1.x * 32 + j];
            unsigned v2 = h32[(size_t)p2.x * 32 + j];
            unsigned v3 = h32[(size_t)p3.x * 32 + j];
            unsigned v4 = h32[(size_t)p4.x * 32 + j];
            unsigned v5 = h32[(size_t)p5.x * 32 + j];
            unsigned v6 = h32[(size_t)p6.x * 32 + j];
            unsigned v7 = h32[(size_t)p7.x * 32 + j];
            float w0 = __int_as_float(p0.y), w1 = __int_as_float(p1.y);
            float w2 = __int_as_float(p2.y), w3 = __int_as_float(p3.y);
            float w4 = __int_as_float(p4.y), w5 = __int_as_float(p5.y);
            float w6 = __int_as_float(p6.y), w7 = __int_as_float(p7.y);
            a0A = fmaf(__uint_as_float(v0 << 16), w0, a0A);
            a0B = fmaf(__uint_as_float(v0 & 0xFFFF0000u), w0, a0B);
            a1A = fmaf(__uint_as_float(v1 << 16), w1, a1A);
            a1B = fmaf(__uint_as_float(v1 & 0xFFFF0000u), w1, a1B);
            a2A = fmaf(__uint_as_float(v2 << 16), w2, a2A);
            a2B = fmaf(__uint_as_float(v2 & 0xFFFF0000u), w2, a2B);
            a3A = fmaf(__uint_as_float(v3 << 16), w3, a3A);
            a3B = fmaf(__uint_as_float(v3 & 0xFFFF0000u), w3, a3B);
            a0A = fmaf(__uint_as_float(v4 << 16), w4, a0A);
            a0B = fmaf(__uint_as_float(v4 & 0xFFFF0000u), w4, a0B);
            a1A = fmaf(__uint_as_float(v5 << 16), w5, a1A);
            a1B = fmaf(__uint_as_float(v5 & 0xFFFF0000u), w5, a1B);
            a2A = fmaf(__uint_as_float(v6 << 16), w6, a2A);
            a2B = fmaf(__uint_as_float(v6 & 0xFFFF0000u), w6, a2B);
            a3A = fmaf(__uint_as_float(v7 << 16), w7, a3A);
            a3B = fmaf(__uint_as_float(v7 & 0xFFFF0000u), w7, a3B);
        }
        for (; i + 2 <= eE; i += 2) {
            int2 p0 = payload2[i + 0];
            int2 p1 = payload2[i + 1];
            unsigned v0 = h32[(size_t)p0.x * 32 + j];
            unsigned v1 = h32[(size_t)p1.x * 32 + j];
            float w0 = __int_as_float(p0.y), w1 = __int_as_float(p1.y);
            a0A = fmaf(__uint_as_float(v0 << 16), w0, a0A);
            a0B = fmaf(__uint_as_float(v0 & 0xFFFF0000u), w0, a0B);
            a1A = fmaf(__uint_as_float(v1 << 16), w1, a1A);
            a1B = fmaf(__uint_as_float(v1 & 0xFFFF0000u), w1, a1B);
        }
        if (i < eE) {
            int2 p0 = payload2[i];
            unsigned v0 = h32[(size_t)p0.x * 32 + j];
            float w0 = __int_as_float(p0.y);
            a0A = fmaf(__uint_as_float(v0 << 16), w0, a0A);
            a0B = fmaf(__uint_as_float(v0 & 0xFFFF0000u), w0, a0B);
        }
        float2 v;
        v.x = fmaxf((a0A + a1A) + (a2A + a3A), 0.f);
        v.y = fmaxf((a0B + a1B) + (a2B + a3B), 0.f);
        *(float2*)(out + (size_t)g * OUT_F + 2 * j) = v;
    }
}

// ---------------------------------------------------------------- launch
extern "C" void kernel_launch(void* const* d_in, const int* in_sizes, int n_in,
                              void* d_out, int out_size, void* d_ws, size_t ws_size,
                              hipStream_t stream) {
    const float* feat = (const float*)d_in[0];
    const float* W    = (const float*)d_in[1];
    const float* ew   = (const float*)d_in[2];
    const int*   src  = (const int*)d_in[3];
    const int*   dst  = (const int*)d_in[4];
    float* out = (float*)d_out;

    const int N = in_sizes[0] / IN_F;
    const int E = in_sizes[2];
    const int nsb = (N + SBNODES - 1) >> LOGSB;

    // workspace layout (8B-aligned first)
    char* ws = (char*)d_ws;
    int2*   payload  = (int2*)ws;   ws += (size_t)E * 8;            // 12.8 MB
    int2*   payload2 = (int2*)ws;   ws += (size_t)E * 8;            // 12.8 MB
    __bf16* h        = (__bf16*)ws; ws += (size_t)N * OUT_F * 2;    // 12.8 MB
    __bf16* wfrag    = (__bf16*)ws; ws += 32 * 64 * 8 * 2;          // 32 KB
    int*    bcnt     = (int*)ws;    ws += (MAXSB + 1) * 4;
    int*    sbbase   = (int*)ws;    ws += (MAXSB + 1) * 4;
    int*    sbcur    = (int*)ws;    ws += MAXSB * 4;
    int*    noff     = (int*)ws;                                    // (N+1)*4

    hipMemsetAsync(bcnt, 0, (size_t)nsb * 4, stream);

    // sort pipeline first, GEMM last -> h is hot in L2/L3 when bgather runs
    hipLaunchKernelGGL(sbhist_kernel, dim3(512), dim3(256), 0, stream, dst, bcnt, E, nsb);
    hipLaunchKernelGGL(sbscan_kernel, dim3(1), dim3(1024), 0, stream, bcnt, sbbase, sbcur, noff, nsb, N, E);
    hipLaunchKernelGGL(sbscatter_kernel, dim3((E + 4095) / 4096), dim3(1024), 0, stream,
                       src, dst, ew, sbcur, payload, E, nsb);
    hipLaunchKernelGGL(fsort_kernel, dim3(nsb), dim3(256), 0, stream, payload, payload2, sbbase, noff, N);
    hipLaunchKernelGGL(wfrag_kernel, dim3(32), dim3(64), 0, stream, W, wfrag);
    hipLaunchKernelGGL(gemm_mfma_kernel, dim3((N + 63) / 64), dim3(256), 0, stream, feat, wfrag, h, N);
    hipLaunchKernelGGL(bgather_kernel, dim3((N + 31) / 32), dim3(256), 0, stream, h, payload2, noff, out, N);
}

// Round 11
// 128.692 us; speedup vs baseline: 5.8789x; 1.0033x over previous
//
#include <hip/hip_runtime.h>

#define IN_F 256
#define OUT_F 64
#define LOGSB 8           // 256 nodes per super-bucket
#define SBNODES 256
#define MAXSB 1024        // supports N <= 262144

typedef __bf16 bf16x8 __attribute__((ext_vector_type(8)));
typedef float f32x4 __attribute__((ext_vector_type(4)));

// ---------------------------------------------------------------- W fragment prep (+ bcnt zero)
__global__ __launch_bounds__(64) void wfrag_kernel(const float* __restrict__ W,
                                                   __bf16* __restrict__ wfrag,
                                                   int* __restrict__ bcnt, int nsb) {
    const int st = blockIdx.x;
    const int l = threadIdx.x;
    if (st == 0)
        for (int i = l; i <= nsb; i += 64) bcnt[i] = 0;
    const int s = st >> 2, t = st & 3;
    const int n = t * 16 + (l & 15);
    const int k0 = s * 32 + (l >> 4) * 8;
    bf16x8 f;
#pragma unroll
    for (int j = 0; j < 8; ++j)
        f[j] = (__bf16)W[(k0 + j) * OUT_F + n];
    *(bf16x8*)(wfrag + (size_t)(st * 64 + l) * 8) = f;
}

// ---------------------------------------------------------------- MFMA GEMM h = feat @ W (bf16 out)
__global__ __launch_bounds__(256) void gemm_mfma_kernel(const float* __restrict__ feat,
                                                        const __bf16* __restrict__ wfrag,
                                                        __bf16* __restrict__ h, int N) {
    const int tid = threadIdx.x;
    const int wv = tid >> 6;
    const int l = tid & 63;
    const int m0 = blockIdx.x * 64 + wv * 16;
    const int q = l >> 4;
    const int row = min(m0 + (l & 15), N - 1);

    const float* __restrict__ arow = feat + (size_t)row * IN_F + q * 8;
    const bf16x8* __restrict__ wf = (const bf16x8*)wfrag; // [32 frags][64 lanes]

    f32x4 acc0 = {0.f, 0.f, 0.f, 0.f};
    f32x4 acc1 = {0.f, 0.f, 0.f, 0.f};
    f32x4 acc2 = {0.f, 0.f, 0.f, 0.f};
    f32x4 acc3 = {0.f, 0.f, 0.f, 0.f};

#pragma unroll
    for (int s = 0; s < 8; ++s) {
        float4 fa0 = *(const float4*)(arow + s * 32);
        float4 fa1 = *(const float4*)(arow + s * 32 + 4);
        bf16x8 a;
        a[0] = (__bf16)fa0.x; a[1] = (__bf16)fa0.y;
        a[2] = (__bf16)fa0.z; a[3] = (__bf16)fa0.w;
        a[4] = (__bf16)fa1.x; a[5] = (__bf16)fa1.y;
        a[6] = (__bf16)fa1.z; a[7] = (__bf16)fa1.w;
        bf16x8 b0 = wf[(s * 4 + 0) * 64 + l];
        bf16x8 b1 = wf[(s * 4 + 1) * 64 + l];
        bf16x8 b2 = wf[(s * 4 + 2) * 64 + l];
        bf16x8 b3 = wf[(s * 4 + 3) * 64 + l];
        acc0 = __builtin_amdgcn_mfma_f32_16x16x32_bf16(a, b0, acc0, 0, 0, 0);
        acc1 = __builtin_amdgcn_mfma_f32_16x16x32_bf16(a, b1, acc1, 0, 0, 0);
        acc2 = __builtin_amdgcn_mfma_f32_16x16x32_bf16(a, b2, acc2, 0, 0, 0);
        acc3 = __builtin_amdgcn_mfma_f32_16x16x32_bf16(a, b3, acc3, 0, 0, 0);
    }

    const int colb = l & 15;
#pragma unroll
    for (int r = 0; r < 4; ++r) {
        int ro = m0 + q * 4 + r;
        if (ro < N) {
            __bf16* hp = h + (size_t)ro * OUT_F + colb;
            hp[0]  = (__bf16)acc0[r];
            hp[16] = (__bf16)acc1[r];
            hp[32] = (__bf16)acc2[r];
            hp[48] = (__bf16)acc3[r];
        }
    }
}

// ---------------------------------------------------------------- super-bucket histogram
__global__ __launch_bounds__(256) void sbhist_kernel(const int* __restrict__ dst,
                                                     int* __restrict__ bcnt, int E, int nsb) {
    __shared__ int hist[MAXSB];
    for (int i = threadIdx.x; i < nsb; i += 256) hist[i] = 0;
    __syncthreads();
    const int stride = gridDim.x * 1024;
    for (int base = (blockIdx.x * 256 + threadIdx.x) * 4; base < E; base += stride) {
        if (base + 4 <= E) {
            int4 d4 = *(const int4*)(dst + base);
            atomicAdd(&hist[d4.x >> LOGSB], 1);
            atomicAdd(&hist[d4.y >> LOGSB], 1);
            atomicAdd(&hist[d4.z >> LOGSB], 1);
            atomicAdd(&hist[d4.w >> LOGSB], 1);
        } else {
            for (int e = base; e < E; ++e) atomicAdd(&hist[dst[e] >> LOGSB], 1);
        }
    }
    __syncthreads();
    for (int i = threadIdx.x; i < nsb; i += 256)
        if (hist[i]) atomicAdd(&bcnt[i], hist[i]);
}

// ---------------------------------------------------------------- super-bucket scan (1 block, nsb <= 1024)
__global__ __launch_bounds__(1024) void sbscan_kernel(const int* __restrict__ bcnt,
                                                      int* __restrict__ sbbase,
                                                      int* __restrict__ sbcur,
                                                      int* __restrict__ noff,
                                                      int nsb, int N, int E) {
    __shared__ int s[1024];
    const int t = threadIdx.x;
    int v = (t < nsb) ? bcnt[t] : 0;
    s[t] = v;
    __syncthreads();
    for (int o = 1; o < 1024; o <<= 1) {
        int x = (t >= o) ? s[t - o] : 0;
        __syncthreads();
        s[t] += x;
        __syncthreads();
    }
    if (t < nsb) {
        int ex = s[t] - v;
        sbbase[t] = ex;
        sbcur[t] = ex;
    }
    if (t == 0) {
        sbbase[nsb] = E;
        noff[N] = E;   // global sentinel
    }
}

// ---------------------------------------------------------------- super-bucket scatter
// Packs local node id (dst & 255) into src bits 24..31.
__global__ __launch_bounds__(1024) void sbscatter_kernel(const int* __restrict__ src,
                                                         const int* __restrict__ dst,
                                                         const float* __restrict__ ew,
                                                         int* __restrict__ sbcur,
                                                         int2* __restrict__ payload,
                                                         int E, int nsb) {
    __shared__ int cnt[MAXSB];
    __shared__ int basearr[MAXSB];
    const int t = threadIdx.x;
    for (int i = t; i < nsb; i += 1024) cnt[i] = 0;
    __syncthreads();

    const int base = (blockIdx.x * 1024 + t) * 4;
    int dd[4] = {0, 0, 0, 0}, ss[4] = {0, 0, 0, 0};
    float ww[4] = {0.f, 0.f, 0.f, 0.f};
    int nv = 0;
    if (base + 4 <= E) {
        int4 d4 = *(const int4*)(dst + base);
        int4 s4 = *(const int4*)(src + base);
        float4 w4 = *(const float4*)(ew + base);
        dd[0] = d4.x; dd[1] = d4.y; dd[2] = d4.z; dd[3] = d4.w;
        ss[0] = s4.x; ss[1] = s4.y; ss[2] = s4.z; ss[3] = s4.w;
        ww[0] = w4.x; ww[1] = w4.y; ww[2] = w4.z; ww[3] = w4.w;
        nv = 4;
    } else if (base < E) {
        nv = E - base;
#pragma unroll 4
        for (int j = 0; j < 4; ++j)
            if (j < nv) { dd[j] = dst[base + j]; ss[j] = src[base + j]; ww[j] = ew[base + j]; }
    }

    int idx[4];
#pragma unroll 4
    for (int j = 0; j < 4; ++j)
        if (j < nv) idx[j] = atomicAdd(&cnt[dd[j] >> LOGSB], 1);
    __syncthreads();

    for (int i = t; i < nsb; i += 1024)
        if (cnt[i]) basearr[i] = atomicAdd(&sbcur[i], cnt[i]);
    __syncthreads();

#pragma unroll 4
    for (int j = 0; j < 4; ++j)
        if (j < nv) {
            int pos = basearr[dd[j] >> LOGSB] + idx[j];
            payload[pos] = make_int2(ss[j] | ((dd[j] & (SBNODES - 1)) << 24),
                                     __float_as_int(ww[j]));
        }
}

// ---------------------------------------------------------------- fine sort within super-bucket
__global__ __launch_bounds__(256) void fsort_kernel(const int2* __restrict__ payload,
                                                    int2* __restrict__ payload2,
                                                    const int* __restrict__ sbbase,
                                                    int* __restrict__ noff, int N) {
    __shared__ int cnt[SBNODES];
    __shared__ int off[SBNODES + 1];
    __shared__ int tick[SBNODES];
    const int t = threadIdx.x;
    const int b = sbbase[blockIdx.x];
    const int e = sbbase[blockIdx.x + 1];
    const int m = e - b;

    cnt[t] = 0;
    __syncthreads();
    for (int i = t; i < m; i += 256)
        atomicAdd(&cnt[((unsigned)payload[b + i].x) >> 24], 1);
    __syncthreads();

    if (t == 0) off[0] = 0;
    off[t + 1] = cnt[t];
    __syncthreads();
    for (int o = 1; o < SBNODES; o <<= 1) {
        int v = (t >= o) ? off[t + 1 - o] : 0;
        __syncthreads();
        off[t + 1] += v;
        __syncthreads();
    }

    const int g = (blockIdx.x << LOGSB) + t;
    if (g < N) noff[g] = b + off[t];
    tick[t] = 0;
    __syncthreads();

    for (int i = t; i < m; i += 256) {
        int2 p = payload[b + i];
        int ld = ((unsigned)p.x) >> 24;
        int pos = b + off[ld] + atomicAdd(&tick[ld], 1);
        payload2[pos] = make_int2(p.x & 0xFFFFFF, p.y);
    }
}

// ---------------------------------------------------------------- gather + ReLU
// Block = 256 thr = 8 half-waves; each half-wave owns its own node. Lane j =
// column pair (2j, 2j+1). 16-deep staggered main loop (two 8-edge groups,
// registers reused) -> ~32 VMEM in flight per half-wave.
#define EDGE8(PBASE, A0A, A0B, A1A, A1B, A2A, A2B, A3A, A3B)                    \
    {                                                                           \
        int2 p0 = (PBASE)[0];                                                   \
        int2 p1 = (PBASE)[1];                                                   \
        int2 p2 = (PBASE)[2];                                                   \
        int2 p3 = (PBASE)[3];                                                   \
        int2 p4 = (PBASE)[4];                                                   \
        int2 p5 = (PBASE)[5];                                                   \
        int2 p6 = (PBASE)[6];                                                   \
        int2 p7 = (PBASE)[7];                                                   \
        unsigned v0 = h32[(size_t)p0.x * 32 + j];                               \
        unsigned v1 = h32[(size_t)p1.x * 32 + j];                               \
        unsigned v2 = h32[(size_t)p2.x * 32 + j];                               \
        unsigned v3 = h32[(size_t)p3.x * 32 + j];                               \
        unsigned v4 = h32[(size_t)p4.x * 32 + j];                               \
        unsigned v5 = h32[(size_t)p5.x * 32 + j];                               \
        unsigned v6 = h32[(size_t)p6.x * 32 + j];                               \
        unsigned v7 = h32[(size_t)p7.x * 32 + j];                               \
        float w0 = __int_as_float(p0.y), w1 = __int_as_float(p1.y);             \
        float w2 = __int_as_float(p2.y), w3 = __int_as_float(p3.y);             \
        float w4 = __int_as_float(p4.y), w5 = __int_as_float(p5.y);             \
        float w6 = __int_as_float(p6.y), w7 = __int_as_float(p7.y);             \
        A0A = fmaf(__uint_as_float(v0 << 16), w0, A0A);                         \
        A0B = fmaf(__uint_as_float(v0 & 0xFFFF0000u), w0, A0B);                 \
        A1A = fmaf(__uint_as_float(v1 << 16), w1, A1A);                         \
        A1B = fmaf(__uint_as_float(v1 & 0xFFFF0000u), w1, A1B);                 \
        A2A = fmaf(__uint_as_float(v2 << 16), w2, A2A);                         \
        A2B = fmaf(__uint_as_float(v2 & 0xFFFF0000u), w2, A2B);                 \
        A3A = fmaf(__uint_as_float(v3 << 16), w3, A3A);                         \
        A3B = fmaf(__uint_as_float(v3 & 0xFFFF0000u), w3, A3B);                 \
        A0A = fmaf(__uint_as_float(v4 << 16), w4, A0A);                         \
        A0B = fmaf(__uint_as_float(v4 & 0xFFFF0000u), w4, A0B);                 \
        A1A = fmaf(__uint_as_float(v5 << 16), w5, A1A);                         \
        A1B = fmaf(__uint_as_float(v5 & 0xFFFF0000u), w5, A1B);                 \
        A2A = fmaf(__uint_as_float(v6 << 16), w6, A2A);                         \
        A2B = fmaf(__uint_as_float(v6 & 0xFFFF0000u), w6, A2B);                 \
        A3A = fmaf(__uint_as_float(v7 << 16), w7, A3A);                         \
        A3B = fmaf(__uint_as_float(v7 & 0xFFFF0000u), w7, A3B);                 \
    }

__global__ __launch_bounds__(256) void bgather_kernel(const __bf16* __restrict__ h,
                                                      const int2* __restrict__ payload2,
                                                      const int* __restrict__ noff,
                                                      float* __restrict__ out, int N) {
    const int t = threadIdx.x;
    const int hw = t >> 5;          // half-wave 0..7
    const int j = t & 31;           // column pair
    const unsigned* __restrict__ h32 = (const unsigned*)h;
    const int g0 = blockIdx.x * 32;

#pragma unroll 1
    for (int k = 0; k < 4; ++k) {
        const int g = g0 + hw + k * 8;
        if (g >= N) continue;
        int i = noff[g];
        const int eE = noff[g + 1];
        float a0A = 0.f, a0B = 0.f, a1A = 0.f, a1B = 0.f;
        float a2A = 0.f, a2B = 0.f, a3A = 0.f, a3B = 0.f;
        float b0A = 0.f, b0B = 0.f, b1A = 0.f, b1B = 0.f;
        float b2A = 0.f, b2B = 0.f, b3A = 0.f, b3B = 0.f;
#pragma unroll 1
        for (; i + 16 <= eE; i += 16) {
            EDGE8(payload2 + i, a0A, a0B, a1A, a1B, a2A, a2B, a3A, a3B)
            EDGE8(payload2 + i + 8, b0A, b0B, b1A, b1B, b2A, b2B, b3A, b3B)
        }
        if (i + 8 <= eE) {
            EDGE8(payload2 + i, a0A, a0B, a1A, a1B, a2A, a2B, a3A, a3B)
            i += 8;
        }
        for (; i + 2 <= eE; i += 2) {
            int2 p0 = payload2[i + 0];
            int2 p1 = payload2[i + 1];
            unsigned v0 = h32[(size_t)p0.x * 32 + j];
            unsigned v1 = h32[(size_t)p1.x * 32 + j];
            float w0 = __int_as_float(p0.y), w1 = __int_as_float(p1.y);
            a0A = fmaf(__uint_as_float(v0 << 16), w0, a0A);
            a0B = fmaf(__uint_as_float(v0 & 0xFFFF0000u), w0, a0B);
            a1A = fmaf(__uint_as_float(v1 << 16), w1, a1A);
            a1B = fmaf(__uint_as_float(v1 & 0xFFFF0000u), w1, a1B);
        }
        if (i < eE) {
            int2 p0 = payload2[i];
            unsigned v0 = h32[(size_t)p0.x * 32 + j];
            float w0 = __int_as_float(p0.y);
            a0A = fmaf(__uint_as_float(v0 << 16), w0, a0A);
            a0B = fmaf(__uint_as_float(v0 & 0xFFFF0000u), w0, a0B);
        }
        float2 v;
        v.x = fmaxf(((a0A + a1A) + (a2A + a3A)) + ((b0A + b1A) + (b2A + b3A)), 0.f);
        v.y = fmaxf(((a0B + a1B) + (a2B + a3B)) + ((b0B + b1B) + (b2B + b3B)), 0.f);
        *(float2*)(out + (size_t)g * OUT_F + 2 * j) = v;
    }
}

// ---------------------------------------------------------------- launch
extern "C" void kernel_launch(void* const* d_in, const int* in_sizes, int n_in,
                              void* d_out, int out_size, void* d_ws, size_t ws_size,
                              hipStream_t stream) {
    const float* feat = (const float*)d_in[0];
    const float* W    = (const float*)d_in[1];
    const float* ew   = (const float*)d_in[2];
    const int*   src  = (const int*)d_in[3];
    const int*   dst  = (const int*)d_in[4];
    float* out = (float*)d_out;

    const int N = in_sizes[0] / IN_F;
    const int E = in_sizes[2];
    const int nsb = (N + SBNODES - 1) >> LOGSB;

    // workspace layout (8B-aligned first)
    char* ws = (char*)d_ws;
    int2*   payload  = (int2*)ws;   ws += (size_t)E * 8;            // 12.8 MB
    int2*   payload2 = (int2*)ws;   ws += (size_t)E * 8;            // 12.8 MB
    __bf16* h        = (__bf16*)ws; ws += (size_t)N * OUT_F * 2;    // 12.8 MB
    __bf16* wfrag    = (__bf16*)ws; ws += 32 * 64 * 8 * 2;          // 32 KB
    int*    bcnt     = (int*)ws;    ws += (MAXSB + 1) * 4;
    int*    sbbase   = (int*)ws;    ws += (MAXSB + 1) * 4;
    int*    sbcur    = (int*)ws;    ws += MAXSB * 4;
    int*    noff     = (int*)ws;                                    // (N+1)*4

    // wfrag first (also zeroes bcnt); GEMM last before gather -> h hot in cache
    hipLaunchKernelGGL(wfrag_kernel, dim3(32), dim3(64), 0, stream, W, wfrag, bcnt, nsb);
    hipLaunchKernelGGL(sbhist_kernel, dim3(512), dim3(256), 0, stream, dst, bcnt, E, nsb);
    hipLaunchKernelGGL(sbscan_kernel, dim3(1), dim3(1024), 0, stream, bcnt, sbbase, sbcur, noff, nsb, N, E);
    hipLaunchKernelGGL(sbscatter_kernel, dim3((E + 4095) / 4096), dim3(1024), 0, stream,
                       src, dst, ew, sbcur, payload, E, nsb);
    hipLaunchKernelGGL(fsort_kernel, dim3(nsb), dim3(256), 0, stream, payload, payload2, sbbase, noff, N);
    hipLaunchKernelGGL(gemm_mfma_kernel, dim3((N + 63) / 64), dim3(256), 0, stream, feat, wfrag, h, N);
    hipLaunchKernelGGL(bgather_kernel, dim3((N + 31) / 32), dim3(256), 0, stream, h, payload2, noff, out, N);
}

// Round 12
// 119.602 us; speedup vs baseline: 6.3258x; 1.0760x over previous
//
#include <hip/hip_runtime.h>

#define IN_F 256
#define OUT_F 64
#define LOGSB 8           // 256 nodes per super-bucket
#define SBNODES 256
#define MAXSB 1024        // supports N <= 262144

typedef __bf16 bf16x8 __attribute__((ext_vector_type(8)));
typedef float f32x4 __attribute__((ext_vector_type(4)));

// ---------------------------------------------------------------- W fragment prep (+ zero bcnt, sbcur)
__global__ __launch_bounds__(64) void wfrag_kernel(const float* __restrict__ W,
                                                   __bf16* __restrict__ wfrag,
                                                   int* __restrict__ bcnt,
                                                   int* __restrict__ sbcur, int nsb) {
    const int st = blockIdx.x;
    const int l = threadIdx.x;
    if (st == 0)
        for (int i = l; i <= nsb; i += 64) bcnt[i] = 0;
    if (st == 1)
        for (int i = l; i < nsb; i += 64) sbcur[i] = 0;
    const int s = st >> 2, t = st & 3;
    const int n = t * 16 + (l & 15);
    const int k0 = s * 32 + (l >> 4) * 8;
    bf16x8 f;
#pragma unroll
    for (int j = 0; j < 8; ++j)
        f[j] = (__bf16)W[(k0 + j) * OUT_F + n];
    *(bf16x8*)(wfrag + (size_t)(st * 64 + l) * 8) = f;
}

// ---------------------------------------------------------------- fused MFMA GEMM + super-bucket histogram
// Blocks [0, gemmBlocks): h = feat @ W (bf16 out). Blocks [gemmBlocks, end):
// grid-stride LDS-privatized histogram of dst>>LOGSB. Independent work; hist's
// atomic latency hides under GEMM's HBM streaming.
__global__ __launch_bounds__(256) void gemmhist_kernel(const float* __restrict__ feat,
                                                       const __bf16* __restrict__ wfrag,
                                                       __bf16* __restrict__ h, int N,
                                                       const int* __restrict__ dst,
                                                       int* __restrict__ bcnt, int E, int nsb,
                                                       int gemmBlocks) {
    __shared__ int histo[MAXSB];
    if ((int)blockIdx.x < gemmBlocks) {
        const int tid = threadIdx.x;
        const int wv = tid >> 6;
        const int l = tid & 63;
        const int m0 = blockIdx.x * 64 + wv * 16;
        const int q = l >> 4;
        const int row = min(m0 + (l & 15), N - 1);

        const float* __restrict__ arow = feat + (size_t)row * IN_F + q * 8;
        const bf16x8* __restrict__ wf = (const bf16x8*)wfrag; // [32 frags][64 lanes]

        f32x4 acc0 = {0.f, 0.f, 0.f, 0.f};
        f32x4 acc1 = {0.f, 0.f, 0.f, 0.f};
        f32x4 acc2 = {0.f, 0.f, 0.f, 0.f};
        f32x4 acc3 = {0.f, 0.f, 0.f, 0.f};

#pragma unroll
        for (int s = 0; s < 8; ++s) {
            float4 fa0 = *(const float4*)(arow + s * 32);
            float4 fa1 = *(const float4*)(arow + s * 32 + 4);
            bf16x8 a;
            a[0] = (__bf16)fa0.x; a[1] = (__bf16)fa0.y;
            a[2] = (__bf16)fa0.z; a[3] = (__bf16)fa0.w;
            a[4] = (__bf16)fa1.x; a[5] = (__bf16)fa1.y;
            a[6] = (__bf16)fa1.z; a[7] = (__bf16)fa1.w;
            bf16x8 b0 = wf[(s * 4 + 0) * 64 + l];
            bf16x8 b1 = wf[(s * 4 + 1) * 64 + l];
            bf16x8 b2 = wf[(s * 4 + 2) * 64 + l];
            bf16x8 b3 = wf[(s * 4 + 3) * 64 + l];
            acc0 = __builtin_amdgcn_mfma_f32_16x16x32_bf16(a, b0, acc0, 0, 0, 0);
            acc1 = __builtin_amdgcn_mfma_f32_16x16x32_bf16(a, b1, acc1, 0, 0, 0);
            acc2 = __builtin_amdgcn_mfma_f32_16x16x32_bf16(a, b2, acc2, 0, 0, 0);
            acc3 = __builtin_amdgcn_mfma_f32_16x16x32_bf16(a, b3, acc3, 0, 0, 0);
        }

        const int colb = l & 15;
#pragma unroll
        for (int r = 0; r < 4; ++r) {
            int ro = m0 + q * 4 + r;
            if (ro < N) {
                __bf16* hp = h + (size_t)ro * OUT_F + colb;
                hp[0]  = (__bf16)acc0[r];
                hp[16] = (__bf16)acc1[r];
                hp[32] = (__bf16)acc2[r];
                hp[48] = (__bf16)acc3[r];
            }
        }
    } else {
        const int hb = blockIdx.x - gemmBlocks;
        const int nhb = gridDim.x - gemmBlocks;
        for (int i = threadIdx.x; i < nsb; i += 256) histo[i] = 0;
        __syncthreads();
        const int stride = nhb * 1024;
        for (int base = (hb * 256 + threadIdx.x) * 4; base < E; base += stride) {
            if (base + 4 <= E) {
                int4 d4 = *(const int4*)(dst + base);
                atomicAdd(&histo[d4.x >> LOGSB], 1);
                atomicAdd(&histo[d4.y >> LOGSB], 1);
                atomicAdd(&histo[d4.z >> LOGSB], 1);
                atomicAdd(&histo[d4.w >> LOGSB], 1);
            } else {
                for (int e = base; e < E; ++e) atomicAdd(&histo[dst[e] >> LOGSB], 1);
            }
        }
        __syncthreads();
        for (int i = threadIdx.x; i < nsb; i += 256)
            if (histo[i]) atomicAdd(&bcnt[i], histo[i]);
    }
}

// ---------------------------------------------------------------- super-bucket scatter (local scan)
// Each block scans bcnt locally (identical result in every block), so no
// separate scan kernel. Reservation = local base + atomic on zero-init sbcur.
__global__ __launch_bounds__(1024) void sbscatter_kernel(const int* __restrict__ src,
                                                         const int* __restrict__ dst,
                                                         const float* __restrict__ ew,
                                                         const int* __restrict__ bcnt,
                                                         int* __restrict__ sbcur,
                                                         int2* __restrict__ payload,
                                                         int E, int nsb) {
    __shared__ int s[1024];
    __shared__ int sbb[MAXSB];
    __shared__ int cnt[MAXSB];
    __shared__ int basearr[MAXSB];
    const int t = threadIdx.x;

    // local exclusive scan of bcnt -> sbb
    int v = (t < nsb) ? bcnt[t] : 0;
    s[t] = v;
    __syncthreads();
    for (int o = 1; o < 1024; o <<= 1) {
        int x = (t >= o) ? s[t - o] : 0;
        __syncthreads();
        s[t] += x;
        __syncthreads();
    }
    if (t < nsb) sbb[t] = s[t] - v;
    for (int i = t; i < nsb; i += 1024) cnt[i] = 0;
    __syncthreads();

    const int base = (blockIdx.x * 1024 + t) * 4;
    int dd[4] = {0, 0, 0, 0}, ss[4] = {0, 0, 0, 0};
    float ww[4] = {0.f, 0.f, 0.f, 0.f};
    int nv = 0;
    if (base + 4 <= E) {
        int4 d4 = *(const int4*)(dst + base);
        int4 s4 = *(const int4*)(src + base);
        float4 w4 = *(const float4*)(ew + base);
        dd[0] = d4.x; dd[1] = d4.y; dd[2] = d4.z; dd[3] = d4.w;
        ss[0] = s4.x; ss[1] = s4.y; ss[2] = s4.z; ss[3] = s4.w;
        ww[0] = w4.x; ww[1] = w4.y; ww[2] = w4.z; ww[3] = w4.w;
        nv = 4;
    } else if (base < E) {
        nv = E - base;
#pragma unroll 4
        for (int j = 0; j < 4; ++j)
            if (j < nv) { dd[j] = dst[base + j]; ss[j] = src[base + j]; ww[j] = ew[base + j]; }
    }

    int idx[4];
#pragma unroll 4
    for (int j = 0; j < 4; ++j)
        if (j < nv) idx[j] = atomicAdd(&cnt[dd[j] >> LOGSB], 1);
    __syncthreads();

    for (int i = t; i < nsb; i += 1024)
        if (cnt[i]) basearr[i] = sbb[i] + atomicAdd(&sbcur[i], cnt[i]);
    __syncthreads();

#pragma unroll 4
    for (int j = 0; j < 4; ++j)
        if (j < nv) {
            int pos = basearr[dd[j] >> LOGSB] + idx[j];
            payload[pos] = make_int2(ss[j] | ((dd[j] & (SBNODES - 1)) << 24),
                                     __float_as_int(ww[j]));
        }
}

// ---------------------------------------------------------------- fine sort within super-bucket
// Computes its own base b by reducing bcnt[0..bid). Caches the first 4096
// edges in registers (one payload read instead of two); overflow streams.
__global__ __launch_bounds__(256) void fsort_kernel(const int2* __restrict__ payload,
                                                    int2* __restrict__ payload2,
                                                    const int* __restrict__ bcnt,
                                                    int* __restrict__ noff,
                                                    int N, int E, int nsb) {
    __shared__ int red[256];
    __shared__ int cnt[SBNODES];
    __shared__ int off[SBNODES + 1];
    __shared__ int tick[SBNODES];
    const int t = threadIdx.x;
    const int bid = blockIdx.x;

    // b = sum of bcnt[0..bid)
    int partial = 0;
    for (int i = t; i < bid; i += 256) partial += bcnt[i];
    red[t] = partial;
    __syncthreads();
    for (int o = 128; o > 0; o >>= 1) {
        if (t < o) red[t] += red[t + o];
        __syncthreads();
    }
    const int b = red[0];
    const int m = bcnt[bid];
    const int mlim = min(m, 4096);

    // register-cache the first mlim edges (16 per thread)
    int2 ed[16];
#pragma unroll
    for (int k = 0; k < 16; ++k) {
        int i = t + k * 256;
        if (i < mlim) ed[k] = payload[b + i];
    }

    cnt[t] = 0;
    __syncthreads();
#pragma unroll
    for (int k = 0; k < 16; ++k) {
        int i = t + k * 256;
        if (i < mlim) atomicAdd(&cnt[((unsigned)ed[k].x) >> 24], 1);
    }
    for (int i = 4096 + t; i < m; i += 256)
        atomicAdd(&cnt[((unsigned)payload[b + i].x) >> 24], 1);
    __syncthreads();

    if (t == 0) off[0] = 0;
    off[t + 1] = cnt[t];
    __syncthreads();
    for (int o = 1; o < SBNODES; o <<= 1) {
        int v2 = (t >= o) ? off[t + 1 - o] : 0;
        __syncthreads();
        off[t + 1] += v2;
        __syncthreads();
    }

    const int g = (bid << LOGSB) + t;
    if (g < N) noff[g] = b + off[t];
    if (bid == 0 && t == 0) noff[N] = E;
    tick[t] = 0;
    __syncthreads();

#pragma unroll
    for (int k = 0; k < 16; ++k) {
        int i = t + k * 256;
        if (i < mlim) {
            int2 p = ed[k];
            int ld = ((unsigned)p.x) >> 24;
            int pos = b + off[ld] + atomicAdd(&tick[ld], 1);
            payload2[pos] = make_int2(p.x & 0xFFFFFF, p.y);
        }
    }
    for (int i = 4096 + t; i < m; i += 256) {
        int2 p = payload[b + i];
        int ld = ((unsigned)p.x) >> 24;
        int pos = b + off[ld] + atomicAdd(&tick[ld], 1);
        payload2[pos] = make_int2(p.x & 0xFFFFFF, p.y);
    }
}

// ---------------------------------------------------------------- gather + ReLU (unchanged from R11)
#define EDGE8(PBASE, A0A, A0B, A1A, A1B, A2A, A2B, A3A, A3B)                    \
    {                                                                           \
        int2 p0 = (PBASE)[0];                                                   \
        int2 p1 = (PBASE)[1];                                                   \
        int2 p2 = (PBASE)[2];                                                   \
        int2 p3 = (PBASE)[3];                                                   \
        int2 p4 = (PBASE)[4];                                                   \
        int2 p5 = (PBASE)[5];                                                   \
        int2 p6 = (PBASE)[6];                                                   \
        int2 p7 = (PBASE)[7];                                                   \
        unsigned v0 = h32[(size_t)p0.x * 32 + j];                               \
        unsigned v1 = h32[(size_t)p1.x * 32 + j];                               \
        unsigned v2 = h32[(size_t)p2.x * 32 + j];                               \
        unsigned v3 = h32[(size_t)p3.x * 32 + j];                               \
        unsigned v4 = h32[(size_t)p4.x * 32 + j];                               \
        unsigned v5 = h32[(size_t)p5.x * 32 + j];                               \
        unsigned v6 = h32[(size_t)p6.x * 32 + j];                               \
        unsigned v7 = h32[(size_t)p7.x * 32 + j];                               \
        float w0 = __int_as_float(p0.y), w1 = __int_as_float(p1.y);             \
        float w2 = __int_as_float(p2.y), w3 = __int_as_float(p3.y);             \
        float w4 = __int_as_float(p4.y), w5 = __int_as_float(p5.y);             \
        float w6 = __int_as_float(p6.y), w7 = __int_as_float(p7.y);             \
        A0A = fmaf(__uint_as_float(v0 << 16), w0, A0A);                         \
        A0B = fmaf(__uint_as_float(v0 & 0xFFFF0000u), w0, A0B);                 \
        A1A = fmaf(__uint_as_float(v1 << 16), w1, A1A);                         \
        A1B = fmaf(__uint_as_float(v1 & 0xFFFF0000u), w1, A1B);                 \
        A2A = fmaf(__uint_as_float(v2 << 16), w2, A2A);                         \
        A2B = fmaf(__uint_as_float(v2 & 0xFFFF0000u), w2, A2B);                 \
        A3A = fmaf(__uint_as_float(v3 << 16), w3, A3A);                         \
        A3B = fmaf(__uint_as_float(v3 & 0xFFFF0000u), w3, A3B);                 \
        A0A = fmaf(__uint_as_float(v4 << 16), w4, A0A);                         \
        A0B = fmaf(__uint_as_float(v4 & 0xFFFF0000u), w4, A0B);                 \
        A1A = fmaf(__uint_as_float(v5 << 16), w5, A1A);                         \
        A1B = fmaf(__uint_as_float(v5 & 0xFFFF0000u), w5, A1B);                 \
        A2A = fmaf(__uint_as_float(v6 << 16), w6, A2A);                         \
        A2B = fmaf(__uint_as_float(v6 & 0xFFFF0000u), w6, A2B);                 \
        A3A = fmaf(__uint_as_float(v7 << 16), w7, A3A);                         \
        A3B = fmaf(__uint_as_float(v7 & 0xFFFF0000u), w7, A3B);                 \
    }

__global__ __launch_bounds__(256) void bgather_kernel(const __bf16* __restrict__ h,
                                                      const int2* __restrict__ payload2,
                                                      const int* __restrict__ noff,
                                                      float* __restrict__ out, int N) {
    const int t = threadIdx.x;
    const int hw = t >> 5;          // half-wave 0..7
    const int j = t & 31;           // column pair
    const unsigned* __restrict__ h32 = (const unsigned*)h;
    const int g0 = blockIdx.x * 32;

#pragma unroll 1
    for (int k = 0; k < 4; ++k) {
        const int g = g0 + hw + k * 8;
        if (g >= N) continue;
        int i = noff[g];
        const int eE = noff[g + 1];
        float a0A = 0.f, a0B = 0.f, a1A = 0.f, a1B = 0.f;
        float a2A = 0.f, a2B = 0.f, a3A = 0.f, a3B = 0.f;
        float b0A = 0.f, b0B = 0.f, b1A = 0.f, b1B = 0.f;
        float b2A = 0.f, b2B = 0.f, b3A = 0.f, b3B = 0.f;
#pragma unroll 1
        for (; i + 16 <= eE; i += 16) {
            EDGE8(payload2 + i, a0A, a0B, a1A, a1B, a2A, a2B, a3A, a3B)
            EDGE8(payload2 + i + 8, b0A, b0B, b1A, b1B, b2A, b2B, b3A, b3B)
        }
        if (i + 8 <= eE) {
            EDGE8(payload2 + i, a0A, a0B, a1A, a1B, a2A, a2B, a3A, a3B)
            i += 8;
        }
        for (; i + 2 <= eE; i += 2) {
            int2 p0 = payload2[i + 0];
            int2 p1 = payload2[i + 1];
            unsigned v0 = h32[(size_t)p0.x * 32 + j];
            unsigned v1 = h32[(size_t)p1.x * 32 + j];
            float w0 = __int_as_float(p0.y), w1 = __int_as_float(p1.y);
            a0A = fmaf(__uint_as_float(v0 << 16), w0, a0A);
            a0B = fmaf(__uint_as_float(v0 & 0xFFFF0000u), w0, a0B);
            a1A = fmaf(__uint_as_float(v1 << 16), w1, a1A);
            a1B = fmaf(__uint_as_float(v1 & 0xFFFF0000u), w1, a1B);
        }
        if (i < eE) {
            int2 p0 = payload2[i];
            unsigned v0 = h32[(size_t)p0.x * 32 + j];
            float w0 = __int_as_float(p0.y);
            a0A = fmaf(__uint_as_float(v0 << 16), w0, a0A);
            a0B = fmaf(__uint_as_float(v0 & 0xFFFF0000u), w0, a0B);
        }
        float2 v;
        v.x = fmaxf(((a0A + a1A) + (a2A + a3A)) + ((b0A + b1A) + (b2A + b3A)), 0.f);
        v.y = fmaxf(((a0B + a1B) + (a2B + a3B)) + ((b0B + b1B) + (b2B + b3B)), 0.f);
        *(float2*)(out + (size_t)g * OUT_F + 2 * j) = v;
    }
}

// ---------------------------------------------------------------- launch
extern "C" void kernel_launch(void* const* d_in, const int* in_sizes, int n_in,
                              void* d_out, int out_size, void* d_ws, size_t ws_size,
                              hipStream_t stream) {
    const float* feat = (const float*)d_in[0];
    const float* W    = (const float*)d_in[1];
    const float* ew   = (const float*)d_in[2];
    const int*   src  = (const int*)d_in[3];
    const int*   dst  = (const int*)d_in[4];
    float* out = (float*)d_out;

    const int N = in_sizes[0] / IN_F;
    const int E = in_sizes[2];
    const int nsb = (N + SBNODES - 1) >> LOGSB;

    // workspace layout (8B-aligned first)
    char* ws = (char*)d_ws;
    int2*   payload  = (int2*)ws;   ws += (size_t)E * 8;            // 12.8 MB
    int2*   payload2 = (int2*)ws;   ws += (size_t)E * 8;            // 12.8 MB
    __bf16* h        = (__bf16*)ws; ws += (size_t)N * OUT_F * 2;    // 12.8 MB
    __bf16* wfrag    = (__bf16*)ws; ws += 32 * 64 * 8 * 2;          // 32 KB
    int*    bcnt     = (int*)ws;    ws += (MAXSB + 1) * 4;
    int*    sbcur    = (int*)ws;    ws += MAXSB * 4;
    int*    noff     = (int*)ws;                                    // (N+1)*4

    const int gemmBlocks = (N + 63) / 64;

    hipLaunchKernelGGL(wfrag_kernel, dim3(32), dim3(64), 0, stream, W, wfrag, bcnt, sbcur, nsb);
    hipLaunchKernelGGL(gemmhist_kernel, dim3(gemmBlocks + 512), dim3(256), 0, stream,
                       feat, wfrag, h, N, dst, bcnt, E, nsb, gemmBlocks);
    hipLaunchKernelGGL(sbscatter_kernel, dim3((E + 4095) / 4096), dim3(1024), 0, stream,
                       src, dst, ew, bcnt, sbcur, payload, E, nsb);
    hipLaunchKernelGGL(fsort_kernel, dim3(nsb), dim3(256), 0, stream,
                       payload, payload2, bcnt, noff, N, E, nsb);
    hipLaunchKernelGGL(bgather_kernel, dim3((N + 31) / 32), dim3(256), 0, stream,
                       h, payload2, noff, out, N);
}

// Round 13
// 117.433 us; speedup vs baseline: 6.4426x; 1.0185x over previous
//
#include <hip/hip_runtime.h>

#define IN_F 256
#define OUT_F 64
#define LOGSB 8           // 256 nodes per super-bucket
#define SBNODES 256
#define MAXSB 1024        // supports N <= 131072 (src must fit 17 bits)

typedef __bf16 bf16x8 __attribute__((ext_vector_type(8)));
typedef float f32x4 __attribute__((ext_vector_type(4)));

// ---------------------------------------------------------------- W fragment prep (+ zero bcnt, sbcur)
__global__ __launch_bounds__(64) void wfrag_kernel(const float* __restrict__ W,
                                                   __bf16* __restrict__ wfrag,
                                                   int* __restrict__ bcnt,
                                                   int* __restrict__ sbcur, int nsb) {
    const int st = blockIdx.x;
    const int l = threadIdx.x;
    if (st == 0)
        for (int i = l; i <= nsb; i += 64) bcnt[i] = 0;
    if (st == 1)
        for (int i = l; i < nsb; i += 64) sbcur[i] = 0;
    const int s = st >> 2, t = st & 3;
    const int n = t * 16 + (l & 15);
    const int k0 = s * 32 + (l >> 4) * 8;
    bf16x8 f;
#pragma unroll
    for (int j = 0; j < 8; ++j)
        f[j] = (__bf16)W[(k0 + j) * OUT_F + n];
    *(bf16x8*)(wfrag + (size_t)(st * 64 + l) * 8) = f;
}

// ---------------------------------------------------------------- fused MFMA GEMM + super-bucket histogram
__global__ __launch_bounds__(256) void gemmhist_kernel(const float* __restrict__ feat,
                                                       const __bf16* __restrict__ wfrag,
                                                       __bf16* __restrict__ h, int N,
                                                       const int* __restrict__ dst,
                                                       int* __restrict__ bcnt, int E, int nsb,
                                                       int gemmBlocks) {
    __shared__ int histo[MAXSB];
    if ((int)blockIdx.x < gemmBlocks) {
        const int tid = threadIdx.x;
        const int wv = tid >> 6;
        const int l = tid & 63;
        const int m0 = blockIdx.x * 64 + wv * 16;
        const int q = l >> 4;
        const int row = min(m0 + (l & 15), N - 1);

        const float* __restrict__ arow = feat + (size_t)row * IN_F + q * 8;
        const bf16x8* __restrict__ wf = (const bf16x8*)wfrag;

        f32x4 acc0 = {0.f, 0.f, 0.f, 0.f};
        f32x4 acc1 = {0.f, 0.f, 0.f, 0.f};
        f32x4 acc2 = {0.f, 0.f, 0.f, 0.f};
        f32x4 acc3 = {0.f, 0.f, 0.f, 0.f};

#pragma unroll
        for (int s = 0; s < 8; ++s) {
            float4 fa0 = *(const float4*)(arow + s * 32);
            float4 fa1 = *(const float4*)(arow + s * 32 + 4);
            bf16x8 a;
            a[0] = (__bf16)fa0.x; a[1] = (__bf16)fa0.y;
            a[2] = (__bf16)fa0.z; a[3] = (__bf16)fa0.w;
            a[4] = (__bf16)fa1.x; a[5] = (__bf16)fa1.y;
            a[6] = (__bf16)fa1.z; a[7] = (__bf16)fa1.w;
            bf16x8 b0 = wf[(s * 4 + 0) * 64 + l];
            bf16x8 b1 = wf[(s * 4 + 1) * 64 + l];
            bf16x8 b2 = wf[(s * 4 + 2) * 64 + l];
            bf16x8 b3 = wf[(s * 4 + 3) * 64 + l];
            acc0 = __builtin_amdgcn_mfma_f32_16x16x32_bf16(a, b0, acc0, 0, 0, 0);
            acc1 = __builtin_amdgcn_mfma_f32_16x16x32_bf16(a, b1, acc1, 0, 0, 0);
            acc2 = __builtin_amdgcn_mfma_f32_16x16x32_bf16(a, b2, acc2, 0, 0, 0);
            acc3 = __builtin_amdgcn_mfma_f32_16x16x32_bf16(a, b3, acc3, 0, 0, 0);
        }

        const int colb = l & 15;
#pragma unroll
        for (int r = 0; r < 4; ++r) {
            int ro = m0 + q * 4 + r;
            if (ro < N) {
                __bf16* hp = h + (size_t)ro * OUT_F + colb;
                hp[0]  = (__bf16)acc0[r];
                hp[16] = (__bf16)acc1[r];
                hp[32] = (__bf16)acc2[r];
                hp[48] = (__bf16)acc3[r];
            }
        }
    } else {
        const int hb = blockIdx.x - gemmBlocks;
        const int nhb = gridDim.x - gemmBlocks;
        for (int i = threadIdx.x; i < nsb; i += 256) histo[i] = 0;
        __syncthreads();
        const int stride = nhb * 1024;
        for (int base = (hb * 256 + threadIdx.x) * 4; base < E; base += stride) {
            if (base + 4 <= E) {
                int4 d4 = *(const int4*)(dst + base);
                atomicAdd(&histo[d4.x >> LOGSB], 1);
                atomicAdd(&histo[d4.y >> LOGSB], 1);
                atomicAdd(&histo[d4.z >> LOGSB], 1);
                atomicAdd(&histo[d4.w >> LOGSB], 1);
            } else {
                for (int e = base; e < E; ++e) atomicAdd(&histo[dst[e] >> LOGSB], 1);
            }
        }
        __syncthreads();
        for (int i = threadIdx.x; i < nsb; i += 256)
            if (histo[i]) atomicAdd(&bcnt[i], histo[i]);
    }
}

// ---------------------------------------------------------------- super-bucket scatter (local scan, 8 edges/thread)
__global__ __launch_bounds__(1024) void sbscatter_kernel(const int* __restrict__ src,
                                                         const int* __restrict__ dst,
                                                         const float* __restrict__ ew,
                                                         const int* __restrict__ bcnt,
                                                         int* __restrict__ sbcur,
                                                         int2* __restrict__ payload,
                                                         int E, int nsb) {
    __shared__ int s[1024];
    __shared__ int sbb[MAXSB];
    __shared__ int cnt[MAXSB];
    __shared__ int basearr[MAXSB];
    const int t = threadIdx.x;

    // local exclusive scan of bcnt -> sbb (identical in every block)
    int v = (t < nsb) ? bcnt[t] : 0;
    s[t] = v;
    __syncthreads();
    for (int o = 1; o < 1024; o <<= 1) {
        int x = (t >= o) ? s[t - o] : 0;
        __syncthreads();
        s[t] += x;
        __syncthreads();
    }
    if (t < nsb) sbb[t] = s[t] - v;
    for (int i = t; i < nsb; i += 1024) cnt[i] = 0;
    __syncthreads();

    const int base = (blockIdx.x * 1024 + t) * 8;
    int dd[8], ss[8];
    float ww[8];
    int nv = 0;
    if (base + 8 <= E) {
        int4 d4a = *(const int4*)(dst + base);
        int4 d4b = *(const int4*)(dst + base + 4);
        int4 s4a = *(const int4*)(src + base);
        int4 s4b = *(const int4*)(src + base + 4);
        float4 w4a = *(const float4*)(ew + base);
        float4 w4b = *(const float4*)(ew + base + 4);
        dd[0] = d4a.x; dd[1] = d4a.y; dd[2] = d4a.z; dd[3] = d4a.w;
        dd[4] = d4b.x; dd[5] = d4b.y; dd[6] = d4b.z; dd[7] = d4b.w;
        ss[0] = s4a.x; ss[1] = s4a.y; ss[2] = s4a.z; ss[3] = s4a.w;
        ss[4] = s4b.x; ss[5] = s4b.y; ss[6] = s4b.z; ss[7] = s4b.w;
        ww[0] = w4a.x; ww[1] = w4a.y; ww[2] = w4a.z; ww[3] = w4a.w;
        ww[4] = w4b.x; ww[5] = w4b.y; ww[6] = w4b.z; ww[7] = w4b.w;
        nv = 8;
    } else if (base < E) {
        nv = E - base;
#pragma unroll 8
        for (int j = 0; j < 8; ++j)
            if (j < nv) { dd[j] = dst[base + j]; ss[j] = src[base + j]; ww[j] = ew[base + j]; }
    }

    int idx[8];
#pragma unroll 8
    for (int j = 0; j < 8; ++j)
        if (j < nv) idx[j] = atomicAdd(&cnt[dd[j] >> LOGSB], 1);
    __syncthreads();

    for (int i = t; i < nsb; i += 1024)
        if (cnt[i]) basearr[i] = sbb[i] + atomicAdd(&sbcur[i], cnt[i]);
    __syncthreads();

#pragma unroll 8
    for (int j = 0; j < 8; ++j)
        if (j < nv) {
            int pos = basearr[dd[j] >> LOGSB] + idx[j];
            payload[pos] = make_int2(ss[j] | ((dd[j] & (SBNODES - 1)) << 24),
                                     __float_as_int(ww[j]));
        }
}

// ---------------------------------------------------------------- fine sort within super-bucket
// Writes PACKED payload2: (src << 15) | (bf16(w) & 0x7FFF). w >= 0 so the sign
// bit is free; src < 2^17. RNE f32->bf16.
__global__ __launch_bounds__(256) void fsort_kernel(const int2* __restrict__ payload,
                                                    unsigned* __restrict__ payload2,
                                                    const int* __restrict__ bcnt,
                                                    int* __restrict__ noff,
                                                    int N, int E, int nsb) {
    __shared__ int red[256];
    __shared__ int cnt[SBNODES];
    __shared__ int off[SBNODES + 1];
    __shared__ int tick[SBNODES];
    const int t = threadIdx.x;
    const int bid = blockIdx.x;

    int partial = 0;
    for (int i = t; i < bid; i += 256) partial += bcnt[i];
    red[t] = partial;
    __syncthreads();
    for (int o = 128; o > 0; o >>= 1) {
        if (t < o) red[t] += red[t + o];
        __syncthreads();
    }
    const int b = red[0];
    const int m = bcnt[bid];
    const int mlim = min(m, 4096);

    int2 ed[16];
#pragma unroll
    for (int k = 0; k < 16; ++k) {
        int i = t + k * 256;
        if (i < mlim) ed[k] = payload[b + i];
    }

    cnt[t] = 0;
    __syncthreads();
#pragma unroll
    for (int k = 0; k < 16; ++k) {
        int i = t + k * 256;
        if (i < mlim) atomicAdd(&cnt[((unsigned)ed[k].x) >> 24], 1);
    }
    for (int i = 4096 + t; i < m; i += 256)
        atomicAdd(&cnt[((unsigned)payload[b + i].x) >> 24], 1);
    __syncthreads();

    if (t == 0) off[0] = 0;
    off[t + 1] = cnt[t];
    __syncthreads();
    for (int o = 1; o < SBNODES; o <<= 1) {
        int v2 = (t >= o) ? off[t + 1 - o] : 0;
        __syncthreads();
        off[t + 1] += v2;
        __syncthreads();
    }

    const int g = (bid << LOGSB) + t;
    if (g < N) noff[g] = b + off[t];
    if (bid == 0 && t == 0) noff[N] = E;
    tick[t] = 0;
    __syncthreads();

#pragma unroll
    for (int k = 0; k < 16; ++k) {
        int i = t + k * 256;
        if (i < mlim) {
            int2 p = ed[k];
            int ld = ((unsigned)p.x) >> 24;
            int pos = b + off[ld] + atomicAdd(&tick[ld], 1);
            unsigned wb = (unsigned)p.y;
            unsigned b16 = (wb + 0x7FFFu + ((wb >> 16) & 1u)) >> 16;   // RNE f32->bf16
            payload2[pos] = (((unsigned)(p.x & 0xFFFFFF)) << 15) | (b16 & 0x7FFFu);
        }
    }
    for (int i = 4096 + t; i < m; i += 256) {
        int2 p = payload[b + i];
        int ld = ((unsigned)p.x) >> 24;
        int pos = b + off[ld] + atomicAdd(&tick[ld], 1);
        unsigned wb = (unsigned)p.y;
        unsigned b16 = (wb + 0x7FFFu + ((wb >> 16) & 1u)) >> 16;
        payload2[pos] = (((unsigned)(p.x & 0xFFFFFF)) << 15) | (b16 & 0x7FFFu);
    }
}

// ---------------------------------------------------------------- gather + ReLU (packed 4B edges)
// Block = 256 thr = 8 half-waves; each half-wave owns its own node. Lane j =
// column pair (2j, 2j+1). 16-deep staggered main loop. Edge decode:
// src = p >> 15; w = bits((p & 0x7FFF) << 16).
#define EDGE8P(PBASE, A0A, A0B, A1A, A1B, A2A, A2B, A3A, A3B)                   \
    {                                                                           \
        unsigned p0 = (PBASE)[0];                                               \
        unsigned p1 = (PBASE)[1];                                               \
        unsigned p2 = (PBASE)[2];                                               \
        unsigned p3 = (PBASE)[3];                                               \
        unsigned p4 = (PBASE)[4];                                               \
        unsigned p5 = (PBASE)[5];                                               \
        unsigned p6 = (PBASE)[6];                                               \
        unsigned p7 = (PBASE)[7];                                               \
        unsigned v0 = h32[(size_t)(p0 >> 15) * 32 + j];                         \
        unsigned v1 = h32[(size_t)(p1 >> 15) * 32 + j];                         \
        unsigned v2 = h32[(size_t)(p2 >> 15) * 32 + j];                         \
        unsigned v3 = h32[(size_t)(p3 >> 15) * 32 + j];                         \
        unsigned v4 = h32[(size_t)(p4 >> 15) * 32 + j];                         \
        unsigned v5 = h32[(size_t)(p5 >> 15) * 32 + j];                         \
        unsigned v6 = h32[(size_t)(p6 >> 15) * 32 + j];                         \
        unsigned v7 = h32[(size_t)(p7 >> 15) * 32 + j];                         \
        float w0 = __uint_as_float((p0 & 0x7FFFu) << 16);                       \
        float w1 = __uint_as_float((p1 & 0x7FFFu) << 16);                       \
        float w2 = __uint_as_float((p2 & 0x7FFFu) << 16);                       \
        float w3 = __uint_as_float((p3 & 0x7FFFu) << 16);                       \
        float w4 = __uint_as_float((p4 & 0x7FFFu) << 16);                       \
        float w5 = __uint_as_float((p5 & 0x7FFFu) << 16);                       \
        float w6 = __uint_as_float((p6 & 0x7FFFu) << 16);                       \
        float w7 = __uint_as_float((p7 & 0x7FFFu) << 16);                       \
        A0A = fmaf(__uint_as_float(v0 << 16), w0, A0A);                         \
        A0B = fmaf(__uint_as_float(v0 & 0xFFFF0000u), w0, A0B);                 \
        A1A = fmaf(__uint_as_float(v1 << 16), w1, A1A);                         \
        A1B = fmaf(__uint_as_float(v1 & 0xFFFF0000u), w1, A1B);                 \
        A2A = fmaf(__uint_as_float(v2 << 16), w2, A2A);                         \
        A2B = fmaf(__uint_as_float(v2 & 0xFFFF0000u), w2, A2B);                 \
        A3A = fmaf(__uint_as_float(v3 << 16), w3, A3A);                         \
        A3B = fmaf(__uint_as_float(v3 & 0xFFFF0000u), w3, A3B);                 \
        A0A = fmaf(__uint_as_float(v4 << 16), w4, A0A);                         \
        A0B = fmaf(__uint_as_float(v4 & 0xFFFF0000u), w4, A0B);                 \
        A1A = fmaf(__uint_as_float(v5 << 16), w5, A1A);                         \
        A1B = fmaf(__uint_as_float(v5 & 0xFFFF0000u), w5, A1B);                 \
        A2A = fmaf(__uint_as_float(v6 << 16), w6, A2A);                         \
        A2B = fmaf(__uint_as_float(v6 & 0xFFFF0000u), w6, A2B);                 \
        A3A = fmaf(__uint_as_float(v7 << 16), w7, A3A);                         \
        A3B = fmaf(__uint_as_float(v7 & 0xFFFF0000u), w7, A3B);                 \
    }

__global__ __launch_bounds__(256) void bgather_kernel(const __bf16* __restrict__ h,
                                                      const unsigned* __restrict__ payload2,
                                                      const int* __restrict__ noff,
                                                      float* __restrict__ out, int N) {
    const int t = threadIdx.x;
    const int hw = t >> 5;
    const int j = t & 31;
    const unsigned* __restrict__ h32 = (const unsigned*)h;
    const int g0 = blockIdx.x * 32;

#pragma unroll 1
    for (int k = 0; k < 4; ++k) {
        const int g = g0 + hw + k * 8;
        if (g >= N) continue;
        int i = noff[g];
        const int eE = noff[g + 1];
        float a0A = 0.f, a0B = 0.f, a1A = 0.f, a1B = 0.f;
        float a2A = 0.f, a2B = 0.f, a3A = 0.f, a3B = 0.f;
        float b0A = 0.f, b0B = 0.f, b1A = 0.f, b1B = 0.f;
        float b2A = 0.f, b2B = 0.f, b3A = 0.f, b3B = 0.f;
#pragma unroll 1
        for (; i + 16 <= eE; i += 16) {
            EDGE8P(payload2 + i, a0A, a0B, a1A, a1B, a2A, a2B, a3A, a3B)
            EDGE8P(payload2 + i + 8, b0A, b0B, b1A, b1B, b2A, b2B, b3A, b3B)
        }
        if (i + 8 <= eE) {
            EDGE8P(payload2 + i, a0A, a0B, a1A, a1B, a2A, a2B, a3A, a3B)
            i += 8;
        }
        for (; i + 2 <= eE; i += 2) {
            unsigned p0 = payload2[i + 0];
            unsigned p1 = payload2[i + 1];
            unsigned v0 = h32[(size_t)(p0 >> 15) * 32 + j];
            unsigned v1 = h32[(size_t)(p1 >> 15) * 32 + j];
            float w0 = __uint_as_float((p0 & 0x7FFFu) << 16);
            float w1 = __uint_as_float((p1 & 0x7FFFu) << 16);
            a0A = fmaf(__uint_as_float(v0 << 16), w0, a0A);
            a0B = fmaf(__uint_as_float(v0 & 0xFFFF0000u), w0, a0B);
            a1A = fmaf(__uint_as_float(v1 << 16), w1, a1A);
            a1B = fmaf(__uint_as_float(v1 & 0xFFFF0000u), w1, a1B);
        }
        if (i < eE) {
            unsigned p0 = payload2[i];
            unsigned v0 = h32[(size_t)(p0 >> 15) * 32 + j];
            float w0 = __uint_as_float((p0 & 0x7FFFu) << 16);
            a0A = fmaf(__uint_as_float(v0 << 16), w0, a0A);
            a0B = fmaf(__uint_as_float(v0 & 0xFFFF0000u), w0, a0B);
        }
        float2 v;
        v.x = fmaxf(((a0A + a1A) + (a2A + a3A)) + ((b0A + b1A) + (b2A + b3A)), 0.f);
        v.y = fmaxf(((a0B + a1B) + (a2B + a3B)) + ((b0B + b1B) + (b2B + b3B)), 0.f);
        *(float2*)(out + (size_t)g * OUT_F + 2 * j) = v;
    }
}

// ---------------------------------------------------------------- launch
extern "C" void kernel_launch(void* const* d_in, const int* in_sizes, int n_in,
                              void* d_out, int out_size, void* d_ws, size_t ws_size,
                              hipStream_t stream) {
    const float* feat = (const float*)d_in[0];
    const float* W    = (const float*)d_in[1];
    const float* ew   = (const float*)d_in[2];
    const int*   src  = (const int*)d_in[3];
    const int*   dst  = (const int*)d_in[4];
    float* out = (float*)d_out;

    const int N = in_sizes[0] / IN_F;
    const int E = in_sizes[2];
    const int nsb = (N + SBNODES - 1) >> LOGSB;

    char* ws = (char*)d_ws;
    int2*     payload  = (int2*)ws;     ws += (size_t)E * 8;          // 12.8 MB
    unsigned* payload2 = (unsigned*)ws; ws += (size_t)E * 4;          //  6.4 MB
    __bf16*   h        = (__bf16*)ws;   ws += (size_t)N * OUT_F * 2;  // 12.8 MB
    __bf16*   wfrag    = (__bf16*)ws;   ws += 32 * 64 * 8 * 2;        // 32 KB
    int*      bcnt     = (int*)ws;      ws += (MAXSB + 1) * 4;
    int*      sbcur    = (int*)ws;      ws += MAXSB * 4;
    int*      noff     = (int*)ws;                                    // (N+1)*4

    const int gemmBlocks = (N + 63) / 64;

    hipLaunchKernelGGL(wfrag_kernel, dim3(32), dim3(64), 0, stream, W, wfrag, bcnt, sbcur, nsb);
    hipLaunchKernelGGL(gemmhist_kernel, dim3(gemmBlocks + 512), dim3(256), 0, stream,
                       feat, wfrag, h, N, dst, bcnt, E, nsb, gemmBlocks);
    hipLaunchKernelGGL(sbscatter_kernel, dim3((E + 8191) / 8192), dim3(1024), 0, stream,
                       src, dst, ew, bcnt, sbcur, payload, E, nsb);
    hipLaunchKernelGGL(fsort_kernel, dim3(nsb), dim3(256), 0, stream,
                       payload, payload2, bcnt, noff, N, E, nsb);
    hipLaunchKernelGGL(bgather_kernel, dim3((N + 31) / 32), dim3(256), 0, stream,
                       h, payload2, noff, out, N);
}